// Round 4
// baseline (268.285 us; speedup 1.0000x reference)
//
#include <hip/hip_runtime.h>
#include <stdint.h>

#define NEGF (-1e30f)

typedef unsigned short ushort_t;
typedef unsigned char uchar_t;
typedef __attribute__((ext_vector_type(4))) float f32x4;
typedef __attribute__((ext_vector_type(8))) int v8i32;

constexpr int cB = 4, cT = 256, cU = 64, cU1 = 65, cV = 1024, cF = 80, cH = 512, cJ = 512;
constexpr int cM = cB * cT * cU1; // 66560
constexpr int cTU = cT * cU1;     // 16640 (per-batch (u,t) plane: u*256+t)
constexpr float LOG2E = 1.4426950408889634f;

// Padé(2,2) tanh + clamp: max err ~0.016, far below fp8-e4m3 half-step; no v_exp.
__device__ __forceinline__ float tanh_fast(float x){
  float t = x * x;
  float num = x * (27.f + t);
  float den = fmaf(9.f, t, 27.f);
  float r = num * __builtin_amdgcn_rcpf(den);
  return fminf(1.f, fmaxf(-1.f, r));
}

// log2-domain logadd: v_exp_f32/v_log_f32 ARE base-2 -> no ln2 scaling muls.
__device__ __forceinline__ float logadd2(float x, float y){
  float m = fmaxf(x, y);
  return m + __builtin_amdgcn_logf(1.f + __builtin_amdgcn_exp2f(-fabsf(x - y)));
}

__device__ __forceinline__ int pk8(float a, float b, float c, float d){
  int v = __builtin_amdgcn_cvt_pk_fp8_f32(a, b, 0, false);
  v = __builtin_amdgcn_cvt_pk_fp8_f32(c, d, v, true);
  return v;
}

// ------------- fused prologue: 4 independent jobs in one dispatch -------------
// bid 0..255  : e[4 rows] = (inputs @ W_enc) @ W_jenc, block-local two-stage
// bid 256..385: dmatb(260,512) = emb[padded] @ W_jdec + b_j
// bid 386..417: WTf8 fp8 K=128 fragment-order transpose of 32*W_out
//               layout: [strip8][kblk4][nt16_8][lane64*32B] (2048 B fragments)
// bid 418..482: zero S[cM]; bid 418 also zeroes out[0] (k_dp atomic target)
__global__ __launch_bounds__(256) void k_pre(
    const float* __restrict__ inputs,
    const float* __restrict__ W_enc, const float* __restrict__ W_jenc,
    const float* __restrict__ emb, const int* __restrict__ targets,
    const float* __restrict__ W_jdec, const float* __restrict__ b_j,
    float* __restrict__ dmatb, float* __restrict__ e,
    const float* __restrict__ W_out, uchar_t* __restrict__ WTf8,
    float* __restrict__ S, float* __restrict__ out_loss)
{
  __shared__ float sA[4][512];
  __shared__ float sIn[4][80];
  int bid = blockIdx.x;
  int tid = threadIdx.x;

  if (bid < 256){
    // ---- e rows m0..m0+3 ----
    int m0 = bid * 4;
    // r20 BUG FIX: 320 elements with 256 threads needs a strided loop (the
    // single `if (tid < 320)` left sIn[3][16..79] uninitialized -> absmax 16).
    for (int i = tid; i < 320; i += 256)
      sIn[i / 80][i % 80] = inputs[m0 * 80 + i];
    __syncthreads();
    int c0 = tid, c1 = tid + 256;
    float a00 = 0.f, a01 = 0.f, a10 = 0.f, a11 = 0.f;
    float a20 = 0.f, a21 = 0.f, a30 = 0.f, a31 = 0.f;
#pragma unroll 8
    for (int k = 0; k < 80; k++){
      float w0 = W_enc[(size_t)k * 512 + c0];
      float w1 = W_enc[(size_t)k * 512 + c1];
      a00 = fmaf(sIn[0][k], w0, a00); a01 = fmaf(sIn[0][k], w1, a01);
      a10 = fmaf(sIn[1][k], w0, a10); a11 = fmaf(sIn[1][k], w1, a11);
      a20 = fmaf(sIn[2][k], w0, a20); a21 = fmaf(sIn[2][k], w1, a21);
      a30 = fmaf(sIn[3][k], w0, a30); a31 = fmaf(sIn[3][k], w1, a31);
    }
    sA[0][c0] = a00; sA[0][c1] = a01;
    sA[1][c0] = a10; sA[1][c1] = a11;
    sA[2][c0] = a20; sA[2][c1] = a21;
    sA[3][c0] = a30; sA[3][c1] = a31;
    __syncthreads();
    float b00 = 0.f, b01 = 0.f, b10 = 0.f, b11 = 0.f;
    float b20 = 0.f, b21 = 0.f, b30 = 0.f, b31 = 0.f;
#pragma unroll 8
    for (int k = 0; k < 512; k++){
      float w0 = W_jenc[(size_t)k * 512 + c0];
      float w1 = W_jenc[(size_t)k * 512 + c1];
      b00 = fmaf(sA[0][k], w0, b00); b01 = fmaf(sA[0][k], w1, b01);
      b10 = fmaf(sA[1][k], w0, b10); b11 = fmaf(sA[1][k], w1, b11);
      b20 = fmaf(sA[2][k], w0, b20); b21 = fmaf(sA[2][k], w1, b21);
      b30 = fmaf(sA[3][k], w0, b30); b31 = fmaf(sA[3][k], w1, b31);
    }
    e[(size_t)(m0 + 0) * 512 + c0] = b00; e[(size_t)(m0 + 0) * 512 + c1] = b01;
    e[(size_t)(m0 + 1) * 512 + c0] = b10; e[(size_t)(m0 + 1) * 512 + c1] = b11;
    e[(size_t)(m0 + 2) * 512 + c0] = b20; e[(size_t)(m0 + 2) * 512 + c1] = b21;
    e[(size_t)(m0 + 3) * 512 + c0] = b30; e[(size_t)(m0 + 3) * 512 + c1] = b31;
  } else if (bid < 386){
    // ---- dmatb = emb[padded] @ W_jdec + b_j ----
    int id = bid - 256;                  // 0..129
    int bx = id & 1, by = id >> 1;
    int m0 = by * 4;
    int col = bx * 256 + tid;
    for (int i = tid; i < 4 * 512; i += 256){
      int r = i >> 9, c = i & 511;
      int row = m0 + r;
      int b = row / cU1, u = row % cU1;
      int src = (u == 0) ? 0 : targets[b * cU + (u - 1)];
      sA[r][c] = emb[(size_t)src * cH + c];
    }
    __syncthreads();
    float a0 = 0.f, a1 = 0.f, a2 = 0.f, a3 = 0.f;
#pragma unroll 8
    for (int k = 0; k < 512; k++){
      float bv = W_jdec[(size_t)k * cJ + col];
      a0 = fmaf(sA[0][k], bv, a0);
      a1 = fmaf(sA[1][k], bv, a1);
      a2 = fmaf(sA[2][k], bv, a2);
      a3 = fmaf(sA[3][k], bv, a3);
    }
    float bb = b_j[col];
    dmatb[(size_t)(m0 + 0) * cJ + col] = a0 + bb;
    dmatb[(size_t)(m0 + 1) * cJ + col] = a1 + bb;
    dmatb[(size_t)(m0 + 2) * cJ + col] = a2 + bb;
    dmatb[(size_t)(m0 + 3) * cJ + col] = a3 + bb;
  } else if (bid < 418){
    // ---- WTf8 K=128 fragments: lane holds col=c16, k = kblk*128+quad*32+0..31 ----
    int id = bid - 386;                  // 0..31
    int strip = id >> 2, kblk = id & 3;
    int lane = tid & 63, nth = tid >> 6;
    int c16 = lane & 15, quad = lane >> 4;
    int jbase = kblk * 128 + quad * 32;
#pragma unroll
    for (int i = 0; i < 2; i++){
      int nt16 = nth * 2 + i;
      int n = strip * 128 + nt16 * 16 + c16;
      unsigned int p[8];
#pragma unroll
      for (int d = 0; d < 8; d++){
        int j0 = jbase + d * 4;
        float w0 = W_out[(size_t)(j0 + 0) * cV + n] * 32.f;
        float w1 = W_out[(size_t)(j0 + 1) * cV + n] * 32.f;
        float w2 = W_out[(size_t)(j0 + 2) * cV + n] * 32.f;
        float w3 = W_out[(size_t)(j0 + 3) * cV + n] * 32.f;
        p[d] = (unsigned)pk8(w0, w1, w2, w3);
      }
      uchar_t* dst = WTf8 + ((size_t)((strip * 4 + kblk) * 8 + nt16)) * 2048 + lane * 32;
      uint4 qa; qa.x = p[0]; qa.y = p[1]; qa.z = p[2]; qa.w = p[3];
      uint4 qb; qb.x = p[4]; qb.y = p[5]; qb.z = p[6]; qb.w = p[7];
      *(uint4*)dst = qa;
      *(uint4*)(dst + 16) = qb;
    }
  } else {
    // ---- zero S: 65 blocks x 256 thr x 4 floats = 66560 ----
    int i = (bid - 418) * 1024 + tid * 4;
    float4 z; z.x = 0.f; z.y = 0.f; z.z = 0.f; z.w = 0.f;
    *(float4*)(S + i) = z;
    if (bid == 418 && tid == 0) out_loss[0] = 0.f;
  }
}

// ------------- H fp8 K=128 fragment-order, coalesced via LDS bounce -------------
// Hbf8 layout per bm tile: [kblk4][mg8][lane64*32B] (2048 B fragments);
// lane holds row = mg*16 + c16, k = kblk*128 + quad*32 + 0..31.
__global__ __launch_bounds__(256) void k_hf(const float* __restrict__ e,
                                            const float* __restrict__ dmatb,
                                            uchar_t* __restrict__ Hbf8){
  __shared__ uchar_t sH[16 * 520];    // 16 rows x 512 B, pad 8 B (8B-aligned reads)
  int tid = threadIdx.x;
  int wid = tid >> 6, lane = tid & 63;
  int c16 = lane & 15, quad = lane >> 4;
  int bm = blockIdx.x;
  int bu = bm >> 1, thalf = bm & 1;
  int b = bu / cU1;
  int t0 = thalf * 128;

  float dj[8];
  const float4* dp = (const float4*)(dmatb + (size_t)bu * cJ + lane * 8);
  float4 dA = dp[0], dB = dp[1];
  dj[0] = dA.x; dj[1] = dA.y; dj[2] = dA.z; dj[3] = dA.w;
  dj[4] = dB.x; dj[5] = dB.y; dj[6] = dB.z; dj[7] = dB.w;

  const float* erow0 = e + ((size_t)(b * cT + t0)) * cJ + lane * 8;
  uchar_t* outb = Hbf8 + (size_t)bm * 65536 + lane * 32;

  for (int mg = 0; mg < 8; mg++){
#pragma unroll
    for (int rr = 0; rr < 4; rr++){
      int rloc = wid * 4 + rr;
      const float* ep = erow0 + ((size_t)(mg * 16 + rloc)) * cJ;
      float4 e0 = *(const float4*)ep;
      float4 e1 = *(const float4*)(ep + 4);
      int v0 = pk8(tanh_fast(e0.x + dj[0]), tanh_fast(e0.y + dj[1]),
                   tanh_fast(e0.z + dj[2]), tanh_fast(e0.w + dj[3]));
      int v1 = pk8(tanh_fast(e1.x + dj[4]), tanh_fast(e1.y + dj[5]),
                   tanh_fast(e1.z + dj[6]), tanh_fast(e1.w + dj[7]));
      uint2 pk; pk.x = (unsigned)v0; pk.y = (unsigned)v1;
      *(uint2*)(sH + rloc * 520 + lane * 8) = pk;
    }
    __syncthreads();
    {
      int kblk = wid;                      // one K=128 fragment per wave
      const uchar_t* src = sH + c16 * 520 + kblk * 128 + quad * 32;
      uint2 q0 = *(const uint2*)(src);
      uint2 q1 = *(const uint2*)(src + 8);
      uint2 q2 = *(const uint2*)(src + 16);
      uint2 q3 = *(const uint2*)(src + 24);
      uint4 qa; qa.x = q0.x; qa.y = q0.y; qa.z = q1.x; qa.w = q1.y;
      uint4 qb; qb.x = q2.x; qb.y = q2.y; qb.z = q3.x; qb.w = q3.y;
      uchar_t* dst = outb + ((size_t)(kblk * 8 + mg)) * 2048;
      *(uint4*)(dst) = qa;
      *(uint4*)(dst + 16) = qb;
    }
    __syncthreads();
  }
}

// ------------- joint GEMM MX-fp8 K=128 (unit scales): 64x64 wave tile -------------
// r3 POST-MORTEM: spill fixed but dur unchanged (59.7us) with MfmaUtil 23% --
// the `unroll 1` + single-streamed af serialized every mt-group behind a fresh
// L2/L3 round trip. r4 fix: explicit X/Y double-buffer of FULL fragment sets
// (hand-named regs, all indices compile-time), loads issued one full MFMA-stage
// (~550cy) ahead. acc 64 + 2x64 fragments ~= 195 VGPR, fits (256,2)'s 256 cap.
#define MF1(a,b,c) __builtin_amdgcn_mfma_scale_f32_16x16x128_f8f6f4( \
    (a), (b), (c), 0, 0, 0, 0x7F7F7F7F, 0, 0x7F7F7F7F)

#define LD_SET(an, bn_, aPk, bPk) \
    an##0 = *(const v8i32*)(aPk);          an##1 = *(const v8i32*)(aPk + 2048); \
    an##2 = *(const v8i32*)(aPk + 4096);   an##3 = *(const v8i32*)(aPk + 6144); \
    bn_##0 = *(const v8i32*)(bPk);         bn_##1 = *(const v8i32*)(bPk + 2048); \
    bn_##2 = *(const v8i32*)(bPk + 4096);  bn_##3 = *(const v8i32*)(bPk + 6144);

#define MFMA_SET(an, bn_) \
    acc[0][0]=MF1(an##0,bn_##0,acc[0][0]); acc[0][1]=MF1(an##0,bn_##1,acc[0][1]); \
    acc[0][2]=MF1(an##0,bn_##2,acc[0][2]); acc[0][3]=MF1(an##0,bn_##3,acc[0][3]); \
    acc[1][0]=MF1(an##1,bn_##0,acc[1][0]); acc[1][1]=MF1(an##1,bn_##1,acc[1][1]); \
    acc[1][2]=MF1(an##1,bn_##2,acc[1][2]); acc[1][3]=MF1(an##1,bn_##3,acc[1][3]); \
    acc[2][0]=MF1(an##2,bn_##0,acc[2][0]); acc[2][1]=MF1(an##2,bn_##1,acc[2][1]); \
    acc[2][2]=MF1(an##2,bn_##2,acc[2][2]); acc[2][3]=MF1(an##2,bn_##3,acc[2][3]); \
    acc[3][0]=MF1(an##3,bn_##0,acc[3][0]); acc[3][1]=MF1(an##3,bn_##1,acc[3][1]); \
    acc[3][2]=MF1(an##3,bn_##2,acc[3][2]); acc[3][3]=MF1(an##3,bn_##3,acc[3][3]);

__global__ __launch_bounds__(256, 2) void k_joint(
    const uchar_t* __restrict__ Hbf8, const uchar_t* __restrict__ WTf8,
    const float* __restrict__ b_out, const int* __restrict__ targets,
    float* __restrict__ S,
    float* __restrict__ blank_g, float* __restrict__ lbl_g)
{
  __shared__ float redS[2][128];

  int tid = threadIdx.x;
  int wid = tid >> 6, lane = tid & 63;
  int quad = lane >> 4, c16 = lane & 15;
  int wm = wid & 1, wn = wid >> 1;
  int bid = blockIdx.x;
  int bm = ((bid >> 6) << 3) + (bid & 7);
  int bn = (bid >> 3) & 7;                       // 128-col strip
  int bu = bm >> 1, thalf = bm & 1;
  int b = bu / cU1, u = bu - b * cU1;
  int tg = (u < cU) ? targets[b * cU + u] : -1;
  int lin0 = bu * cT + thalf * 128;              // (b,u,t)-linear base

  f32x4 acc[4][4];
#pragma unroll
  for (int i = 0; i < 4; i++)
#pragma unroll
    for (int j = 0; j < 4; j++)
      acc[i][j] = (f32x4){0.f, 0.f, 0.f, 0.f};

  const uchar_t* aP = Hbf8 + (size_t)bm * 65536 + (size_t)(wm * 4) * 2048 + lane * 32;
  const uchar_t* bP = WTf8 + (size_t)bn * 65536 + (size_t)(wn * 4) * 2048 + lane * 32;

  v8i32 aX0, aX1, aX2, aX3, bX0, bX1, bX2, bX3;
  v8i32 aY0, aY1, aY2, aY3, bY0, bY1, bY2, bY3;

  LD_SET(aX, bX, aP, bP)                           // kblk 0 -> X
  LD_SET(aY, bY, (aP + 16384), (bP + 16384))       // kblk 1 -> Y
  MFMA_SET(aX, bX)                                 // compute k0 (k2 loads below
  LD_SET(aX, bX, (aP + 32768), (bP + 32768))       //  hoistable above the MFMAs)
  MFMA_SET(aY, bY)                                 // compute k1
  LD_SET(aY, bY, (aP + 49152), (bP + 49152))       // kblk 3 -> Y
  MFMA_SET(aX, bX)                                 // compute k2
  MFMA_SET(aY, bY)                                 // compute k3

  float bv[4];
#pragma unroll
  for (int nt = 0; nt < 4; nt++) bv[nt] = b_out[bn * 128 + (wn * 4 + nt) * 16 + c16] * LOG2E;

  bool ownL = (tg >= 0) && ((tg >> 7) == bn) && (((tg >> 6) & 1) == wn);
  int ntO = (tg >> 4) & 3;
  int tgc = tg & 15;
  const float descale2 = LOG2E / 32.f;  // undo *32 on W_out fp8 AND go log2-domain

#pragma unroll
  for (int mt = 0; mt < 4; mt++){
#pragma unroll
    for (int r = 0; r < 4; r++){
      int rl = wm * 64 + mt * 16 + quad * 4 + r;  // C/D: col=lane&15, row=quad*4+reg (m89)
      float l[4];
#pragma unroll
      for (int nt = 0; nt < 4; nt++) l[nt] = fmaf(acc[mt][nt][r], descale2, bv[nt]);
      if (bn == 0 && wn == 0 && c16 == 0) blank_g[lin0 + rl] = l[0];
      if (ownL && c16 == tgc){
        float v = l[0];
#pragma unroll
        for (int k = 1; k < 4; k++) v = (ntO == k) ? l[k] : v;
        lbl_g[lin0 + rl] = v;
      }
      float s = __builtin_amdgcn_exp2f(l[0]) + __builtin_amdgcn_exp2f(l[1])
              + __builtin_amdgcn_exp2f(l[2]) + __builtin_amdgcn_exp2f(l[3]);
      s += __shfl_xor(s, 1, 64);
      s += __shfl_xor(s, 2, 64);
      s += __shfl_xor(s, 4, 64);
      s += __shfl_xor(s, 8, 64);
      if (c16 == 0) redS[wn][rl] = s;
    }
  }
  __syncthreads();
  if (tid < 128)
    atomicAdd(&S[lin0 + tid], redS[0][tid] + redS[1][tid]);
}

// ------------- RNN-T alpha DP: SKIP-2 diagonals, log2 domain, fused-LSE staging -------------
// blank_g/lbl_g arrive ALREADY in log2 domain (k_joint epilogue) -> staging is
// just x - log2(S). Everything else as the verified r1 version.
__global__ __launch_bounds__(256) void k_dp(
    const float* __restrict__ S, const float* __restrict__ blank_g,
    const float* __restrict__ lbl_g,
    const int* __restrict__ in_len, const int* __restrict__ tgt_len,
    float* __restrict__ out)
{
  __shared__ float sbb[cTU];   // 65 KB, (u,t): index u*256+t  (log2 domain)
  __shared__ float slb[cTU];   // 65 KB
  __shared__ float sS[256];    // alpha[t][63] history (lane 63)
  int b = blockIdx.x;
  int tl  = tgt_len[b];                // 32..64
  size_t base = (size_t)b * cTU;
  for (int i = threadIdx.x; i < cTU / 4; i += 256){
    int row = i >> 6;                  // float4 never crosses a 256-elem row
    if (row > tl) continue;            // rows > tl unread by any live lane
    float4 sv = ((const float4*)(S + base))[i];
    float4 bvv = ((const float4*)(blank_g + base))[i];
    float4 ls;
    ls.x = __builtin_amdgcn_logf(sv.x); ls.y = __builtin_amdgcn_logf(sv.y);
    ls.z = __builtin_amdgcn_logf(sv.z); ls.w = __builtin_amdgcn_logf(sv.w);
    float4 bo;
    bo.x = bvv.x - ls.x; bo.y = bvv.y - ls.y;
    bo.z = bvv.z - ls.z; bo.w = bvv.w - ls.w;
    ((float4*)sbb)[i] = bo;
    float4 lo;
    if (row < tl){
      float4 lv = ((const float4*)(lbl_g + base))[i];
      lo.x = lv.x - ls.x; lo.y = lv.y - ls.y;
      lo.z = lv.z - ls.z; lo.w = lv.w - ls.w;
    } else {
      lo.x = NEGF; lo.y = NEGF; lo.z = NEGF; lo.w = NEGF;
    }
    ((float4*)slb)[i] = lo;
  }
  __syncthreads();
  if (threadIdx.x >= 64) return;

  int u = threadIdx.x;                 // 0..63
  int til = in_len[b] - 1;
  bool cap64 = (tl == 64);
  bool isTL = (u == tl);
  const float* pbu  = sbb + (u << 8);
  const float* pbu1 = sbb + (((u >= 1) ? u - 1 : 0) << 8);
  const float* plu1 = slb + (((u >= 1) ? u - 1 : 0) << 8);
  const float* plu2 = slb + (((u >= 2) ? u - 2 : 0) << 8);
  bool u1 = (u >= 1), u2 = (u >= 2);
  float fb = pbu[til];                 // blank at (u, til); used by lane tl only
  int shA1 = (u - 1) << 2;             // bpermute byte addrs; underflow wraps to
  int shA2 = (u - 2) << 2;             // lane 63 -> value killed by NEG masking

  float A = (u == 0) ? 0.f : NEGF;     // alpha on even diagonal d = 2g (log2)
  float res = 0.f;

  auto ld = [&](const float* p, int i, bool ok) -> float {
    float x = p[i & 255];              // wrap stays inside sbb/slb
    return (ok & ((unsigned)i < 256u)) ? x : NEGF;
  };

  int i0 = -u;
  float o0 = ld(pbu,  i0,     true);   // bb[t-2][u]
  float o1 = ld(pbu,  i0 + 1, true);   // bb[t-1][u]
  float o2 = ld(plu1, i0 + 1, u1);     // lb[t-1][u-1]
  float o3 = ld(pbu1, i0 + 1, u1);     // bb[t-1][u-1]
  float o4 = ld(plu1, i0 + 2, u1);     // lb[t][u-1]
  float o5 = ld(plu2, i0 + 2, u2);     // lb[t][u-2]

#pragma unroll 3
  for (int g = 0; g < 159; g++){
    // shuffles FIRST (depend on prev A) so the prefetch reads below stay behind
    // them in lgkm order -> waiting for up1/up2 is lgkmcnt(6), not a full drain
    float up1 = __int_as_float(__builtin_amdgcn_ds_bpermute(shA1, __float_as_int(A)));
    float up2 = __int_as_float(__builtin_amdgcn_ds_bpermute(shA2, __float_as_int(A)));

    int i0n = i0 + 2;
    float n0 = ld(pbu,  i0n,     true);
    float n1 = ld(pbu,  i0n + 1, true);
    float n2 = ld(plu1, i0n + 1, u1);
    float n3 = ld(pbu1, i0n + 1, u1);
    float n4 = ld(plu1, i0n + 2, u1);
    float n5 = ld(plu2, i0n + 2, u2);

    float C0 = o0 + o1;
    float C1 = logadd2(o2 + o1, o3 + o4);
    float C2 = o5 + o4;

    float am0 = A + o0, am1 = up1 + o2;
    float Amid = logadd2(am0, am1);
    bool tv1 = ((unsigned)(i0 + 1) < 256u);
    Amid = tv1 ? Amid : NEGF;

    float a0 = A + C0, a1 = up1 + C1, a2 = up2 + C2;
    float m3 = fmaxf(fmaxf(a0, a1), a2);          // v_max3
    float s3 = __builtin_amdgcn_exp2f(a0 - m3) + __builtin_amdgcn_exp2f(a1 - m3)
             + __builtin_amdgcn_exp2f(a2 - m3);
    float Anew = m3 + __builtin_amdgcn_logf(s3);
    bool tv2 = ((unsigned)(i0 + 2) < 256u);
    Anew = tv2 ? Anew : NEGF;

    if (isTL && (i0 + 1) == til) res = Amid + fb;
    if (isTL && (i0 + 2) == til) res = Anew + fb;
    if (u == 63){
      if (tv1) sS[i0 + 1] = Amid;
      if (tv2) sS[i0 + 2] = Anew;
    }
    A = Anew;
    i0 = i0n;
    o0 = n0; o1 = n1; o2 = n2; o3 = n3; o4 = n4; o5 = n5;
  }

  if (cap64){
    const float* pb64 = sbb + (64 << 8);
    const float* pl63 = slb + (63 << 8);
    float A64 = sS[0] + pl63[0];       // alpha[0][64]
    for (int t = 1; t <= til; t++)
      A64 = logadd2(A64 + pb64[t - 1], sS[t] + pl63[t]);
    if (u == 0) res = A64 + pb64[til];
  }

  // butterfly-sum broadcasts the single captured value (others hold 0)
  res += __shfl_xor(res, 1, 64);
  res += __shfl_xor(res, 2, 64);
  res += __shfl_xor(res, 4, 64);
  res += __shfl_xor(res, 8, 64);
  res += __shfl_xor(res, 16, 64);
  res += __shfl_xor(res, 32, 64);
  if (u == 0) atomicAdd(out, -0.17328679513998632f * res);  // -0.25 * ln2 (log2->ln)
}

extern "C" void kernel_launch(void* const* d_in, const int* in_sizes, int n_in,
                              void* d_out, int out_size, void* d_ws, size_t ws_size,
                              hipStream_t stream)
{
  (void)in_sizes; (void)n_in; (void)out_size; (void)ws_size;
  const float* inputs = (const float*)d_in[0];   // (4,256,80)
  const float* W_enc  = (const float*)d_in[1];   // (80,512)
  const float* emb    = (const float*)d_in[2];   // (1024,512)
  const float* W_jenc = (const float*)d_in[3];   // (512,512)
  const float* W_jdec = (const float*)d_in[4];   // (512,512)
  const float* b_j    = (const float*)d_in[5];   // (512)
  const float* W_out  = (const float*)d_in[6];   // (512,1024)
  const float* b_out  = (const float*)d_in[7];   // (1024)
  const int* targets  = (const int*)d_in[8];     // (4,64)
  const int* in_len   = (const int*)d_in[9];     // (4)
  const int* tgt_len  = (const int*)d_in[10];    // (4)

  char* w = (char*)d_ws;
  auto alloc = [&](size_t bytes){ char* p = w; w += (bytes + 255) & ~(size_t)255; return p; };
  float* e       = (float*)alloc((size_t)1024 * 512 * 4);
  float* dmatb   = (float*)alloc((size_t)260 * 512 * 4);
  float* blank_g = (float*)alloc((size_t)cM * 4);
  float* lbl_g   = (float*)alloc((size_t)cM * 4);
  float* S       = (float*)alloc((size_t)cM * 4);
  uchar_t* Hbf8  = (uchar_t*)alloc((size_t)520 * 65536);
  uchar_t* WTf8  = (uchar_t*)alloc((size_t)8 * 65536);

  k_pre<<<483, 256, 0, stream>>>(inputs, W_enc, W_jenc, emb, targets, W_jdec, b_j,
                                 dmatb, e, W_out, WTf8, S, (float*)d_out);
  k_hf<<<520, 256, 0, stream>>>(e, dmatb, Hbf8);
  k_joint<<<4160, 256, 0, stream>>>(Hbf8, WTf8, b_out, targets, S, blank_g, lbl_g);
  k_dp<<<4, 256, 0, stream>>>(S, blank_g, lbl_g, in_len, tgt_len, (float*)d_out);
}

// Round 5
// 225.721 us; speedup vs baseline: 1.1886x; 1.1886x over previous
//
#include <hip/hip_runtime.h>
#include <stdint.h>

#define NEGF (-1e30f)

typedef unsigned short ushort_t;
typedef unsigned char uchar_t;
typedef __attribute__((ext_vector_type(2))) long v2i64;
typedef __attribute__((ext_vector_type(4))) float f32x4;

constexpr int cB = 4, cT = 256, cU = 64, cU1 = 65, cV = 1024, cF = 80, cH = 512, cJ = 512;
constexpr int cM = cB * cT * cU1; // 66560
constexpr int cTU = cT * cU1;     // 16640 (per-batch (u,t) plane: u*256+t)
constexpr float LOG2E = 1.4426950408889634f;

// Padé(2,2) tanh + clamp: max err ~0.016, far below fp8-e4m3 half-step; no v_exp.
__device__ __forceinline__ float tanh_fast(float x){
  float t = x * x;
  float num = x * (27.f + t);
  float den = fmaf(9.f, t, 27.f);
  float r = num * __builtin_amdgcn_rcpf(den);
  return fminf(1.f, fmaxf(-1.f, r));
}

// log2-domain logadd: v_exp_f32/v_log_f32 ARE base-2 -> no ln2 scaling muls.
__device__ __forceinline__ float logadd2(float x, float y){
  float m = fmaxf(x, y);
  return m + __builtin_amdgcn_logf(1.f + __builtin_amdgcn_exp2f(-fabsf(x - y)));
}

__device__ __forceinline__ int pk8(float a, float b, float c, float d){
  int v = __builtin_amdgcn_cvt_pk_fp8_f32(a, b, 0, false);
  v = __builtin_amdgcn_cvt_pk_fp8_f32(c, d, v, true);
  return v;
}

// ------------- fused prologue: 4 independent jobs in one dispatch -------------
// bid 0..255  : e[4 rows] = (inputs @ W_enc) @ W_jenc, block-local two-stage
// bid 256..385: dmatb(260,512) = emb[padded] @ W_jdec + b_j
// bid 386..417: WTf8 fp8 fragment-order transpose of 32*W_out (2-ks-packed, K=32)
// bid 418..482: zero S[cM]; bid 418 also zeroes out[0] (k_dp atomic target)
__global__ __launch_bounds__(256) void k_pre(
    const float* __restrict__ inputs,
    const float* __restrict__ W_enc, const float* __restrict__ W_jenc,
    const float* __restrict__ emb, const int* __restrict__ targets,
    const float* __restrict__ W_jdec, const float* __restrict__ b_j,
    float* __restrict__ dmatb, float* __restrict__ e,
    const float* __restrict__ W_out, uchar_t* __restrict__ WTf8,
    float* __restrict__ S, float* __restrict__ out_loss)
{
  __shared__ float sA[4][512];
  __shared__ float sIn[4][80];
  int bid = blockIdx.x;
  int tid = threadIdx.x;

  if (bid < 256){
    // ---- e rows m0..m0+3 ----
    int m0 = bid * 4;
    // r20 BUG FIX: 320 elements with 256 threads needs a strided loop (the
    // single `if (tid < 320)` left sIn[3][16..79] uninitialized -> absmax 16).
    for (int i = tid; i < 320; i += 256)
      sIn[i / 80][i % 80] = inputs[m0 * 80 + i];
    __syncthreads();
    int c0 = tid, c1 = tid + 256;
    float a00 = 0.f, a01 = 0.f, a10 = 0.f, a11 = 0.f;
    float a20 = 0.f, a21 = 0.f, a30 = 0.f, a31 = 0.f;
#pragma unroll 8
    for (int k = 0; k < 80; k++){
      float w0 = W_enc[(size_t)k * 512 + c0];
      float w1 = W_enc[(size_t)k * 512 + c1];
      a00 = fmaf(sIn[0][k], w0, a00); a01 = fmaf(sIn[0][k], w1, a01);
      a10 = fmaf(sIn[1][k], w0, a10); a11 = fmaf(sIn[1][k], w1, a11);
      a20 = fmaf(sIn[2][k], w0, a20); a21 = fmaf(sIn[2][k], w1, a21);
      a30 = fmaf(sIn[3][k], w0, a30); a31 = fmaf(sIn[3][k], w1, a31);
    }
    sA[0][c0] = a00; sA[0][c1] = a01;
    sA[1][c0] = a10; sA[1][c1] = a11;
    sA[2][c0] = a20; sA[2][c1] = a21;
    sA[3][c0] = a30; sA[3][c1] = a31;
    __syncthreads();
    float b00 = 0.f, b01 = 0.f, b10 = 0.f, b11 = 0.f;
    float b20 = 0.f, b21 = 0.f, b30 = 0.f, b31 = 0.f;
#pragma unroll 8
    for (int k = 0; k < 512; k++){
      float w0 = W_jenc[(size_t)k * 512 + c0];
      float w1 = W_jenc[(size_t)k * 512 + c1];
      b00 = fmaf(sA[0][k], w0, b00); b01 = fmaf(sA[0][k], w1, b01);
      b10 = fmaf(sA[1][k], w0, b10); b11 = fmaf(sA[1][k], w1, b11);
      b20 = fmaf(sA[2][k], w0, b20); b21 = fmaf(sA[2][k], w1, b21);
      b30 = fmaf(sA[3][k], w0, b30); b31 = fmaf(sA[3][k], w1, b31);
    }
    e[(size_t)(m0 + 0) * 512 + c0] = b00; e[(size_t)(m0 + 0) * 512 + c1] = b01;
    e[(size_t)(m0 + 1) * 512 + c0] = b10; e[(size_t)(m0 + 1) * 512 + c1] = b11;
    e[(size_t)(m0 + 2) * 512 + c0] = b20; e[(size_t)(m0 + 2) * 512 + c1] = b21;
    e[(size_t)(m0 + 3) * 512 + c0] = b30; e[(size_t)(m0 + 3) * 512 + c1] = b31;
  } else if (bid < 386){
    // ---- dmatb = emb[padded] @ W_jdec + b_j ----
    int id = bid - 256;                  // 0..129
    int bx = id & 1, by = id >> 1;
    int m0 = by * 4;
    int col = bx * 256 + tid;
    for (int i = tid; i < 4 * 512; i += 256){
      int r = i >> 9, c = i & 511;
      int row = m0 + r;
      int b = row / cU1, u = row % cU1;
      int src = (u == 0) ? 0 : targets[b * cU + (u - 1)];
      sA[r][c] = emb[(size_t)src * cH + c];
    }
    __syncthreads();
    float a0 = 0.f, a1 = 0.f, a2 = 0.f, a3 = 0.f;
#pragma unroll 8
    for (int k = 0; k < 512; k++){
      float bv = W_jdec[(size_t)k * cJ + col];
      a0 = fmaf(sA[0][k], bv, a0);
      a1 = fmaf(sA[1][k], bv, a1);
      a2 = fmaf(sA[2][k], bv, a2);
      a3 = fmaf(sA[3][k], bv, a3);
    }
    float bb = b_j[col];
    dmatb[(size_t)(m0 + 0) * cJ + col] = a0 + bb;
    dmatb[(size_t)(m0 + 1) * cJ + col] = a1 + bb;
    dmatb[(size_t)(m0 + 2) * cJ + col] = a2 + bb;
    dmatb[(size_t)(m0 + 3) * cJ + col] = a3 + bb;
  } else if (bid < 418){
    // ---- WTf8[((bn4*8+ksp)*16 + nt16)*1024 + lane*16]  (K=32, 2-ks-packed) ----
    int id = bid - 386;                  // 0..31
    int bn = id & 3, ksp = id >> 2;      // ksp 0..7
    int lane = tid & 63, nth = tid >> 6;
    int c16 = lane & 15, quad = lane >> 4;
    int jA = ksp * 64 + quad * 8;
#pragma unroll
    for (int i = 0; i < 4; i++){
      int nt16 = nth * 4 + i;
      int n = bn * 256 + nt16 * 16 + c16;
      unsigned int p[4];
#pragma unroll
      for (int h = 0; h < 4; h++){
        int j0 = jA + (h >> 1) * 32 + (h & 1) * 4;
        float w0 = W_out[(size_t)(j0 + 0) * cV + n] * 32.f;
        float w1 = W_out[(size_t)(j0 + 1) * cV + n] * 32.f;
        float w2 = W_out[(size_t)(j0 + 2) * cV + n] * 32.f;
        float w3 = W_out[(size_t)(j0 + 3) * cV + n] * 32.f;
        p[h] = (unsigned)pk8(w0, w1, w2, w3);
      }
      uint4 pack; pack.x = p[0]; pack.y = p[1]; pack.z = p[2]; pack.w = p[3];
      *(uint4*)(WTf8 + (((size_t)(bn * 8 + ksp) * 16 + nt16) * 64 + lane) * 16) = pack;
    }
  } else {
    // ---- zero S: 65 blocks x 256 thr x 4 floats = 66560 ----
    int i = (bid - 418) * 1024 + tid * 4;
    float4 z; z.x = 0.f; z.y = 0.f; z.z = 0.f; z.w = 0.f;
    *(float4*)(S + i) = z;
    if (bid == 418 && tid == 0) out_loss[0] = 0.f;
  }
}

// ------------- H fp8 fragment-order (K=32), t-minor, coalesced via LDS bounce -------------
__global__ __launch_bounds__(256) void k_hf(const float* __restrict__ e,
                                            const float* __restrict__ dmatb,
                                            uchar_t* __restrict__ Hbf8){
  __shared__ uchar_t sH[16 * 520];    // 16 rows x 512 B, pad 8 B
  int tid = threadIdx.x;
  int wid = tid >> 6, lane = tid & 63;
  int c16 = lane & 15, quad = lane >> 4;
  int bm = blockIdx.x;
  int bu = bm >> 1, thalf = bm & 1;
  int b = bu / cU1;
  int t0 = thalf * 128;

  float dj[8];
  const float4* dp = (const float4*)(dmatb + (size_t)bu * cJ + lane * 8);
  float4 dA = dp[0], dB = dp[1];
  dj[0] = dA.x; dj[1] = dA.y; dj[2] = dA.z; dj[3] = dA.w;
  dj[4] = dB.x; dj[5] = dB.y; dj[6] = dB.z; dj[7] = dB.w;

  const float* erow0 = e + ((size_t)(b * cT + t0)) * cJ + lane * 8;
  uchar_t* outb = Hbf8 + (size_t)bm * 65536 + lane * 16;

  for (int mg = 0; mg < 8; mg++){
#pragma unroll
    for (int rr = 0; rr < 4; rr++){
      int rloc = wid * 4 + rr;
      const float* ep = erow0 + ((size_t)(mg * 16 + rloc)) * cJ;
      float4 e0 = *(const float4*)ep;
      float4 e1 = *(const float4*)(ep + 4);
      int v0 = pk8(tanh_fast(e0.x + dj[0]), tanh_fast(e0.y + dj[1]),
                   tanh_fast(e0.z + dj[2]), tanh_fast(e0.w + dj[3]));
      int v1 = pk8(tanh_fast(e1.x + dj[4]), tanh_fast(e1.y + dj[5]),
                   tanh_fast(e1.z + dj[6]), tanh_fast(e1.w + dj[7]));
      uint2 pk; pk.x = (unsigned)v0; pk.y = (unsigned)v1;
      *(uint2*)(sH + rloc * 520 + lane * 8) = pk;
    }
    __syncthreads();
#pragma unroll
    for (int q = 0; q < 2; q++){
      int ksp = wid * 2 + q;
      uint2 lo = *(const uint2*)(sH + c16 * 520 + ksp * 64 + quad * 8);
      uint2 hi = *(const uint2*)(sH + c16 * 520 + ksp * 64 + 32 + quad * 8);
      uint4 pack; pack.x = lo.x; pack.y = lo.y; pack.z = hi.x; pack.w = hi.y;
      *(uint4*)(outb + ((size_t)ksp * 8 + mg) * 1024) = pack;
    }
    __syncthreads();
  }
}

// ------------- joint GEMM fp8 K=32: 64x64 wave tile, FOUR blocks/CU -------------
// r3/r4 POST-MORTEM: K=32 (60us, MfmaUtil 46%) and MX K=128 (60us, MfmaUtil 23%)
// run at IDENTICAL duration -> not MFMA-bound; latency-bound at 3 blocks/CU.
// MX needs fragment registers the allocator won't give (r2/r4 both spilled).
// So: keep the proven K=32 body (60 VGPR + 64 AGPR = 124 regs) and raise
// occupancy to 4 blocks/CU via (256,4) -- 124 <= 512/4 = 128-reg cap, no spill.
// Epilogue in log2 domain (exp2 direct; LOG2E folded into descale/bias).
__global__ __launch_bounds__(256, 4) void k_joint(
    const uchar_t* __restrict__ Hbf8, const uchar_t* __restrict__ WTf8,
    const float* __restrict__ b_out, const int* __restrict__ targets,
    float* __restrict__ S,
    float* __restrict__ blank_g, float* __restrict__ lbl_g)
{
  __shared__ float redS[2][128];

  int tid = threadIdx.x;
  int wid = tid >> 6, lane = tid & 63;
  int quad = lane >> 4, c16 = lane & 15;
  int wm = wid & 1, wn = wid >> 1;
  int bid = blockIdx.x;
  int bm = ((bid >> 6) << 3) + (bid & 7);
  int bn = (bid >> 3) & 7;                       // 128-col strip
  int bu = bm >> 1, thalf = bm & 1;
  int b = bu / cU1, u = bu - b * cU1;
  int tg = (u < cU) ? targets[b * cU + u] : -1;
  int lin0 = bu * cT + thalf * 128;              // (b,u,t)-linear base

  f32x4 acc[4][4];
#pragma unroll
  for (int i = 0; i < 4; i++)
#pragma unroll
    for (int j = 0; j < 4; j++)
      acc[i][j] = (f32x4){0.f, 0.f, 0.f, 0.f};

  const uchar_t* aP = Hbf8 + (size_t)bm * 65536 + (wm * 4) * 1024 + lane * 16;
  const uchar_t* bP = WTf8 + (size_t)(bn >> 1) * 131072 + ((bn & 1) * 8 + wn * 4) * 1024 + lane * 16;

#pragma unroll
  for (int ksp = 0; ksp < 8; ksp++){
    v2i64 af[4], bf[4];
#pragma unroll
    for (int mt = 0; mt < 4; mt++)
      af[mt] = *(const v2i64*)(aP + (size_t)ksp * 8192 + mt * 1024);
#pragma unroll
    for (int nt = 0; nt < 4; nt++)
      bf[nt] = *(const v2i64*)(bP + (size_t)ksp * 16384 + nt * 1024);
#pragma unroll
    for (int h = 0; h < 2; h++)
#pragma unroll
      for (int mt = 0; mt < 4; mt++)
#pragma unroll
        for (int nt = 0; nt < 4; nt++)
          acc[mt][nt] = __builtin_amdgcn_mfma_f32_16x16x32_fp8_fp8(af[mt][h], bf[nt][h], acc[mt][nt], 0, 0, 0);
  }

  float bv[4];
#pragma unroll
  for (int nt = 0; nt < 4; nt++) bv[nt] = b_out[bn * 128 + (wn * 4 + nt) * 16 + c16] * LOG2E;

  bool ownL = (tg >= 0) && ((tg >> 7) == bn) && (((tg >> 6) & 1) == wn);
  int ntO = (tg >> 4) & 3;
  int tgc = tg & 15;
  const float descale2 = LOG2E / 32.f;  // undo *32 on W_out fp8 AND go log2-domain

#pragma unroll
  for (int mt = 0; mt < 4; mt++){
#pragma unroll
    for (int r = 0; r < 4; r++){
      int rl = wm * 64 + mt * 16 + quad * 4 + r;  // C/D: col=lane&15, row=quad*4+reg (m89)
      float l[4];
#pragma unroll
      for (int nt = 0; nt < 4; nt++) l[nt] = fmaf(acc[mt][nt][r], descale2, bv[nt]);
      if (bn == 0 && wn == 0 && c16 == 0) blank_g[lin0 + rl] = l[0];
      if (ownL && c16 == tgc){
        float v = l[0];
#pragma unroll
        for (int k = 1; k < 4; k++) v = (ntO == k) ? l[k] : v;
        lbl_g[lin0 + rl] = v;
      }
      float s = __builtin_amdgcn_exp2f(l[0]) + __builtin_amdgcn_exp2f(l[1])
              + __builtin_amdgcn_exp2f(l[2]) + __builtin_amdgcn_exp2f(l[3]);
      s += __shfl_xor(s, 1, 64);
      s += __shfl_xor(s, 2, 64);
      s += __shfl_xor(s, 4, 64);
      s += __shfl_xor(s, 8, 64);
      if (c16 == 0) redS[wn][rl] = s;
    }
  }
  __syncthreads();
  if (tid < 128)
    atomicAdd(&S[lin0 + tid], redS[0][tid] + redS[1][tid]);
}

// ------------- RNN-T alpha DP: SKIP-2 diagonals, log2 domain, fused-LSE staging -------------
// blank_g/lbl_g arrive ALREADY in log2 domain (k_joint epilogue) -> staging is
// just x - log2(S). Everything else as the verified r1 version.
__global__ __launch_bounds__(256) void k_dp(
    const float* __restrict__ S, const float* __restrict__ blank_g,
    const float* __restrict__ lbl_g,
    const int* __restrict__ in_len, const int* __restrict__ tgt_len,
    float* __restrict__ out)
{
  __shared__ float sbb[cTU];   // 65 KB, (u,t): index u*256+t  (log2 domain)
  __shared__ float slb[cTU];   // 65 KB
  __shared__ float sS[256];    // alpha[t][63] history (lane 63)
  int b = blockIdx.x;
  int tl  = tgt_len[b];                // 32..64
  size_t base = (size_t)b * cTU;
  for (int i = threadIdx.x; i < cTU / 4; i += 256){
    int row = i >> 6;                  // float4 never crosses a 256-elem row
    if (row > tl) continue;            // rows > tl unread by any live lane
    float4 sv = ((const float4*)(S + base))[i];
    float4 bvv = ((const float4*)(blank_g + base))[i];
    float4 ls;
    ls.x = __builtin_amdgcn_logf(sv.x); ls.y = __builtin_amdgcn_logf(sv.y);
    ls.z = __builtin_amdgcn_logf(sv.z); ls.w = __builtin_amdgcn_logf(sv.w);
    float4 bo;
    bo.x = bvv.x - ls.x; bo.y = bvv.y - ls.y;
    bo.z = bvv.z - ls.z; bo.w = bvv.w - ls.w;
    ((float4*)sbb)[i] = bo;
    float4 lo;
    if (row < tl){
      float4 lv = ((const float4*)(lbl_g + base))[i];
      lo.x = lv.x - ls.x; lo.y = lv.y - ls.y;
      lo.z = lv.z - ls.z; lo.w = lv.w - ls.w;
    } else {
      lo.x = NEGF; lo.y = NEGF; lo.z = NEGF; lo.w = NEGF;
    }
    ((float4*)slb)[i] = lo;
  }
  __syncthreads();
  if (threadIdx.x >= 64) return;

  int u = threadIdx.x;                 // 0..63
  int til = in_len[b] - 1;
  bool cap64 = (tl == 64);
  bool isTL = (u == tl);
  const float* pbu  = sbb + (u << 8);
  const float* pbu1 = sbb + (((u >= 1) ? u - 1 : 0) << 8);
  const float* plu1 = slb + (((u >= 1) ? u - 1 : 0) << 8);
  const float* plu2 = slb + (((u >= 2) ? u - 2 : 0) << 8);
  bool u1 = (u >= 1), u2 = (u >= 2);
  float fb = pbu[til];                 // blank at (u, til); used by lane tl only
  int shA1 = (u - 1) << 2;             // bpermute byte addrs; underflow wraps to
  int shA2 = (u - 2) << 2;             // lane 63 -> value killed by NEG masking

  float A = (u == 0) ? 0.f : NEGF;     // alpha on even diagonal d = 2g (log2)
  float res = 0.f;

  auto ld = [&](const float* p, int i, bool ok) -> float {
    float x = p[i & 255];              // wrap stays inside sbb/slb
    return (ok & ((unsigned)i < 256u)) ? x : NEGF;
  };

  int i0 = -u;
  float o0 = ld(pbu,  i0,     true);   // bb[t-2][u]
  float o1 = ld(pbu,  i0 + 1, true);   // bb[t-1][u]
  float o2 = ld(plu1, i0 + 1, u1);     // lb[t-1][u-1]
  float o3 = ld(pbu1, i0 + 1, u1);     // bb[t-1][u-1]
  float o4 = ld(plu1, i0 + 2, u1);     // lb[t][u-1]
  float o5 = ld(plu2, i0 + 2, u2);     // lb[t][u-2]

#pragma unroll 3
  for (int g = 0; g < 159; g++){
    // shuffles FIRST (depend on prev A) so the prefetch reads below stay behind
    // them in lgkm order -> waiting for up1/up2 is lgkmcnt(6), not a full drain
    float up1 = __int_as_float(__builtin_amdgcn_ds_bpermute(shA1, __float_as_int(A)));
    float up2 = __int_as_float(__builtin_amdgcn_ds_bpermute(shA2, __float_as_int(A)));

    int i0n = i0 + 2;
    float n0 = ld(pbu,  i0n,     true);
    float n1 = ld(pbu,  i0n + 1, true);
    float n2 = ld(plu1, i0n + 1, u1);
    float n3 = ld(pbu1, i0n + 1, u1);
    float n4 = ld(plu1, i0n + 2, u1);
    float n5 = ld(plu2, i0n + 2, u2);

    float C0 = o0 + o1;
    float C1 = logadd2(o2 + o1, o3 + o4);
    float C2 = o5 + o4;

    float am0 = A + o0, am1 = up1 + o2;
    float Amid = logadd2(am0, am1);
    bool tv1 = ((unsigned)(i0 + 1) < 256u);
    Amid = tv1 ? Amid : NEGF;

    float a0 = A + C0, a1 = up1 + C1, a2 = up2 + C2;
    float m3 = fmaxf(fmaxf(a0, a1), a2);          // v_max3
    float s3 = __builtin_amdgcn_exp2f(a0 - m3) + __builtin_amdgcn_exp2f(a1 - m3)
             + __builtin_amdgcn_exp2f(a2 - m3);
    float Anew = m3 + __builtin_amdgcn_logf(s3);
    bool tv2 = ((unsigned)(i0 + 2) < 256u);
    Anew = tv2 ? Anew : NEGF;

    if (isTL && (i0 + 1) == til) res = Amid + fb;
    if (isTL && (i0 + 2) == til) res = Anew + fb;
    if (u == 63){
      if (tv1) sS[i0 + 1] = Amid;
      if (tv2) sS[i0 + 2] = Anew;
    }
    A = Anew;
    i0 = i0n;
    o0 = n0; o1 = n1; o2 = n2; o3 = n3; o4 = n4; o5 = n5;
  }

  if (cap64){
    const float* pb64 = sbb + (64 << 8);
    const float* pl63 = slb + (63 << 8);
    float A64 = sS[0] + pl63[0];       // alpha[0][64]
    for (int t = 1; t <= til; t++)
      A64 = logadd2(A64 + pb64[t - 1], sS[t] + pl63[t]);
    if (u == 0) res = A64 + pb64[til];
  }

  // butterfly-sum broadcasts the single captured value (others hold 0)
  res += __shfl_xor(res, 1, 64);
  res += __shfl_xor(res, 2, 64);
  res += __shfl_xor(res, 4, 64);
  res += __shfl_xor(res, 8, 64);
  res += __shfl_xor(res, 16, 64);
  res += __shfl_xor(res, 32, 64);
  if (u == 0) atomicAdd(out, -0.17328679513998632f * res);  // -0.25 * ln2 (log2->ln)
}

extern "C" void kernel_launch(void* const* d_in, const int* in_sizes, int n_in,
                              void* d_out, int out_size, void* d_ws, size_t ws_size,
                              hipStream_t stream)
{
  (void)in_sizes; (void)n_in; (void)out_size; (void)ws_size;
  const float* inputs = (const float*)d_in[0];   // (4,256,80)
  const float* W_enc  = (const float*)d_in[1];   // (80,512)
  const float* emb    = (const float*)d_in[2];   // (1024,512)
  const float* W_jenc = (const float*)d_in[3];   // (512,512)
  const float* W_jdec = (const float*)d_in[4];   // (512,512)
  const float* b_j    = (const float*)d_in[5];   // (512)
  const float* W_out  = (const float*)d_in[6];   // (512,1024)
  const float* b_out  = (const float*)d_in[7];   // (1024)
  const int* targets  = (const int*)d_in[8];     // (4,64)
  const int* in_len   = (const int*)d_in[9];     // (4)
  const int* tgt_len  = (const int*)d_in[10];    // (4)

  char* w = (char*)d_ws;
  auto alloc = [&](size_t bytes){ char* p = w; w += (bytes + 255) & ~(size_t)255; return p; };
  float* e       = (float*)alloc((size_t)1024 * 512 * 4);
  float* dmatb   = (float*)alloc((size_t)260 * 512 * 4);
  float* blank_g = (float*)alloc((size_t)cM * 4);
  float* lbl_g   = (float*)alloc((size_t)cM * 4);
  float* S       = (float*)alloc((size_t)cM * 4);
  uchar_t* Hbf8  = (uchar_t*)alloc((size_t)520 * 65536);
  uchar_t* WTf8  = (uchar_t*)alloc((size_t)4 * 131072);

  k_pre<<<483, 256, 0, stream>>>(inputs, W_enc, W_jenc, emb, targets, W_jdec, b_j,
                                 dmatb, e, W_out, WTf8, S, (float*)d_out);
  k_hf<<<520, 256, 0, stream>>>(e, dmatb, Hbf8);
  k_joint<<<4160, 256, 0, stream>>>(Hbf8, WTf8, b_out, targets, S, blank_g, lbl_g);
  k_dp<<<4, 256, 0, stream>>>(S, blank_g, lbl_g, in_len, tgt_len, (float*)d_out);
}

// Round 6
// 223.448 us; speedup vs baseline: 1.2007x; 1.0102x over previous
//
#include <hip/hip_runtime.h>
#include <stdint.h>

#define NEGF (-1e30f)

typedef unsigned short ushort_t;
typedef unsigned char uchar_t;
typedef __attribute__((ext_vector_type(2))) long v2i64;
typedef __attribute__((ext_vector_type(4))) float f32x4;

constexpr int cB = 4, cT = 256, cU = 64, cU1 = 65, cV = 1024, cF = 80, cH = 512, cJ = 512;
constexpr int cM = cB * cT * cU1; // 66560
constexpr int cTU = cT * cU1;     // 16640 (per-batch (u,t) plane: u*256+t)
constexpr float LOG2E = 1.4426950408889634f;

// Padé(2,2) tanh + clamp: max err ~0.016, far below fp8-e4m3 half-step; no v_exp.
__device__ __forceinline__ float tanh_fast(float x){
  float t = x * x;
  float num = x * (27.f + t);
  float den = fmaf(9.f, t, 27.f);
  float r = num * __builtin_amdgcn_rcpf(den);
  return fminf(1.f, fmaxf(-1.f, r));
}

// log2-domain logadd: v_exp_f32/v_log_f32 ARE base-2 -> no ln2 scaling muls.
__device__ __forceinline__ float logadd2(float x, float y){
  float m = fmaxf(x, y);
  return m + __builtin_amdgcn_logf(1.f + __builtin_amdgcn_exp2f(-fabsf(x - y)));
}

__device__ __forceinline__ int pk8(float a, float b, float c, float d){
  int v = __builtin_amdgcn_cvt_pk_fp8_f32(a, b, 0, false);
  v = __builtin_amdgcn_cvt_pk_fp8_f32(c, d, v, true);
  return v;
}

// ------------- fused prologue: 4 independent jobs in one dispatch -------------
// bid 0..255  : e[4 rows] = (inputs @ W_enc) @ W_jenc, block-local two-stage
// bid 256..385: dmatb(260,512) = emb[padded] @ W_jdec + b_j
// bid 386..417: WTf8 fp8 fragment-order transpose of 32*W_out (2-ks-packed, K=32)
// bid 418..482: zero S[cM]; bid 418 also zeroes out[0] (k_dp atomic target)
__global__ __launch_bounds__(256) void k_pre(
    const float* __restrict__ inputs,
    const float* __restrict__ W_enc, const float* __restrict__ W_jenc,
    const float* __restrict__ emb, const int* __restrict__ targets,
    const float* __restrict__ W_jdec, const float* __restrict__ b_j,
    float* __restrict__ dmatb, float* __restrict__ e,
    const float* __restrict__ W_out, uchar_t* __restrict__ WTf8,
    float* __restrict__ S, float* __restrict__ out_loss)
{
  __shared__ float sA[4][512];
  __shared__ float sIn[4][80];
  int bid = blockIdx.x;
  int tid = threadIdx.x;

  if (bid < 256){
    // ---- e rows m0..m0+3 ----
    int m0 = bid * 4;
    // r20 BUG FIX: 320 elements with 256 threads needs a strided loop (the
    // single `if (tid < 320)` left sIn[3][16..79] uninitialized -> absmax 16).
    for (int i = tid; i < 320; i += 256)
      sIn[i / 80][i % 80] = inputs[m0 * 80 + i];
    __syncthreads();
    int c0 = tid, c1 = tid + 256;
    float a00 = 0.f, a01 = 0.f, a10 = 0.f, a11 = 0.f;
    float a20 = 0.f, a21 = 0.f, a30 = 0.f, a31 = 0.f;
#pragma unroll 8
    for (int k = 0; k < 80; k++){
      float w0 = W_enc[(size_t)k * 512 + c0];
      float w1 = W_enc[(size_t)k * 512 + c1];
      a00 = fmaf(sIn[0][k], w0, a00); a01 = fmaf(sIn[0][k], w1, a01);
      a10 = fmaf(sIn[1][k], w0, a10); a11 = fmaf(sIn[1][k], w1, a11);
      a20 = fmaf(sIn[2][k], w0, a20); a21 = fmaf(sIn[2][k], w1, a21);
      a30 = fmaf(sIn[3][k], w0, a30); a31 = fmaf(sIn[3][k], w1, a31);
    }
    sA[0][c0] = a00; sA[0][c1] = a01;
    sA[1][c0] = a10; sA[1][c1] = a11;
    sA[2][c0] = a20; sA[2][c1] = a21;
    sA[3][c0] = a30; sA[3][c1] = a31;
    __syncthreads();
    float b00 = 0.f, b01 = 0.f, b10 = 0.f, b11 = 0.f;
    float b20 = 0.f, b21 = 0.f, b30 = 0.f, b31 = 0.f;
#pragma unroll 8
    for (int k = 0; k < 512; k++){
      float w0 = W_jenc[(size_t)k * 512 + c0];
      float w1 = W_jenc[(size_t)k * 512 + c1];
      b00 = fmaf(sA[0][k], w0, b00); b01 = fmaf(sA[0][k], w1, b01);
      b10 = fmaf(sA[1][k], w0, b10); b11 = fmaf(sA[1][k], w1, b11);
      b20 = fmaf(sA[2][k], w0, b20); b21 = fmaf(sA[2][k], w1, b21);
      b30 = fmaf(sA[3][k], w0, b30); b31 = fmaf(sA[3][k], w1, b31);
    }
    e[(size_t)(m0 + 0) * 512 + c0] = b00; e[(size_t)(m0 + 0) * 512 + c1] = b01;
    e[(size_t)(m0 + 1) * 512 + c0] = b10; e[(size_t)(m0 + 1) * 512 + c1] = b11;
    e[(size_t)(m0 + 2) * 512 + c0] = b20; e[(size_t)(m0 + 2) * 512 + c1] = b21;
    e[(size_t)(m0 + 3) * 512 + c0] = b30; e[(size_t)(m0 + 3) * 512 + c1] = b31;
  } else if (bid < 386){
    // ---- dmatb = emb[padded] @ W_jdec + b_j ----
    int id = bid - 256;                  // 0..129
    int bx = id & 1, by = id >> 1;
    int m0 = by * 4;
    int col = bx * 256 + tid;
    for (int i = tid; i < 4 * 512; i += 256){
      int r = i >> 9, c = i & 511;
      int row = m0 + r;
      int b = row / cU1, u = row % cU1;
      int src = (u == 0) ? 0 : targets[b * cU + (u - 1)];
      sA[r][c] = emb[(size_t)src * cH + c];
    }
    __syncthreads();
    float a0 = 0.f, a1 = 0.f, a2 = 0.f, a3 = 0.f;
#pragma unroll 8
    for (int k = 0; k < 512; k++){
      float bv = W_jdec[(size_t)k * cJ + col];
      a0 = fmaf(sA[0][k], bv, a0);
      a1 = fmaf(sA[1][k], bv, a1);
      a2 = fmaf(sA[2][k], bv, a2);
      a3 = fmaf(sA[3][k], bv, a3);
    }
    float bb = b_j[col];
    dmatb[(size_t)(m0 + 0) * cJ + col] = a0 + bb;
    dmatb[(size_t)(m0 + 1) * cJ + col] = a1 + bb;
    dmatb[(size_t)(m0 + 2) * cJ + col] = a2 + bb;
    dmatb[(size_t)(m0 + 3) * cJ + col] = a3 + bb;
  } else if (bid < 418){
    // ---- WTf8[((bn4*8+ksp)*16 + nt16)*1024 + lane*16]  (K=32, 2-ks-packed) ----
    int id = bid - 386;                  // 0..31
    int bn = id & 3, ksp = id >> 2;      // ksp 0..7
    int lane = tid & 63, nth = tid >> 6;
    int c16 = lane & 15, quad = lane >> 4;
    int jA = ksp * 64 + quad * 8;
#pragma unroll
    for (int i = 0; i < 4; i++){
      int nt16 = nth * 4 + i;
      int n = bn * 256 + nt16 * 16 + c16;
      unsigned int p[4];
#pragma unroll
      for (int h = 0; h < 4; h++){
        int j0 = jA + (h >> 1) * 32 + (h & 1) * 4;
        float w0 = W_out[(size_t)(j0 + 0) * cV + n] * 32.f;
        float w1 = W_out[(size_t)(j0 + 1) * cV + n] * 32.f;
        float w2 = W_out[(size_t)(j0 + 2) * cV + n] * 32.f;
        float w3 = W_out[(size_t)(j0 + 3) * cV + n] * 32.f;
        p[h] = (unsigned)pk8(w0, w1, w2, w3);
      }
      uint4 pack; pack.x = p[0]; pack.y = p[1]; pack.z = p[2]; pack.w = p[3];
      *(uint4*)(WTf8 + (((size_t)(bn * 8 + ksp) * 16 + nt16) * 64 + lane) * 16) = pack;
    }
  } else {
    // ---- zero S: 65 blocks x 256 thr x 4 floats = 66560 ----
    int i = (bid - 418) * 1024 + tid * 4;
    float4 z; z.x = 0.f; z.y = 0.f; z.z = 0.f; z.w = 0.f;
    *(float4*)(S + i) = z;
    if (bid == 418 && tid == 0) out_loss[0] = 0.f;
  }
}

// ------------- H fp8 fragment-order (K=32), t-minor, coalesced via LDS bounce -------------
__global__ __launch_bounds__(256) void k_hf(const float* __restrict__ e,
                                            const float* __restrict__ dmatb,
                                            uchar_t* __restrict__ Hbf8){
  __shared__ uchar_t sH[16 * 520];    // 16 rows x 512 B, pad 8 B
  int tid = threadIdx.x;
  int wid = tid >> 6, lane = tid & 63;
  int c16 = lane & 15, quad = lane >> 4;
  int bm = blockIdx.x;
  int bu = bm >> 1, thalf = bm & 1;
  int b = bu / cU1;
  int t0 = thalf * 128;

  float dj[8];
  const float4* dp = (const float4*)(dmatb + (size_t)bu * cJ + lane * 8);
  float4 dA = dp[0], dB = dp[1];
  dj[0] = dA.x; dj[1] = dA.y; dj[2] = dA.z; dj[3] = dA.w;
  dj[4] = dB.x; dj[5] = dB.y; dj[6] = dB.z; dj[7] = dB.w;

  const float* erow0 = e + ((size_t)(b * cT + t0)) * cJ + lane * 8;
  uchar_t* outb = Hbf8 + (size_t)bm * 65536 + lane * 16;

  for (int mg = 0; mg < 8; mg++){
#pragma unroll
    for (int rr = 0; rr < 4; rr++){
      int rloc = wid * 4 + rr;
      const float* ep = erow0 + ((size_t)(mg * 16 + rloc)) * cJ;
      float4 e0 = *(const float4*)ep;
      float4 e1 = *(const float4*)(ep + 4);
      int v0 = pk8(tanh_fast(e0.x + dj[0]), tanh_fast(e0.y + dj[1]),
                   tanh_fast(e0.z + dj[2]), tanh_fast(e0.w + dj[3]));
      int v1 = pk8(tanh_fast(e1.x + dj[4]), tanh_fast(e1.y + dj[5]),
                   tanh_fast(e1.z + dj[6]), tanh_fast(e1.w + dj[7]));
      uint2 pk; pk.x = (unsigned)v0; pk.y = (unsigned)v1;
      *(uint2*)(sH + rloc * 520 + lane * 8) = pk;
    }
    __syncthreads();
#pragma unroll
    for (int q = 0; q < 2; q++){
      int ksp = wid * 2 + q;
      uint2 lo = *(const uint2*)(sH + c16 * 520 + ksp * 64 + quad * 8);
      uint2 hi = *(const uint2*)(sH + c16 * 520 + ksp * 64 + 32 + quad * 8);
      uint4 pack; pack.x = lo.x; pack.y = lo.y; pack.z = hi.x; pack.w = hi.y;
      *(uint4*)(outb + ((size_t)ksp * 8 + mg) * 1024) = pack;
    }
    __syncthreads();
  }
}

// ------------- joint GEMM fp8 K=32: 64x64 wave tile, X/Y software pipeline -------------
// r5 POST-MORTEM: (256,4) changed nothing (occ ~36%, 60us, VGPR 60). Compiler
// keeps ONE fragment set live (VGPR 60 = 32 frag + addr) -> every ksp stage's
// 8 loads land exposed (~200-600cy L2) with only ~154cy of MFMA to hide them.
// r6: explicit 1-stage-ahead pipeline with TWO named v2i64 sets (64 frag VGPR,
// half of r4's spilling v8i32 version): load(k+1) issued before MFMA(k).
// ~95 VGPR + 64 AGPR ~= 160 fits (256,3)'s ~170 cap. Spill tripwire:
// WRITE_SIZE must stay ~2.6MB.
__global__ __launch_bounds__(256, 3) void k_joint(
    const uchar_t* __restrict__ Hbf8, const uchar_t* __restrict__ WTf8,
    const float* __restrict__ b_out, const int* __restrict__ targets,
    float* __restrict__ S,
    float* __restrict__ blank_g, float* __restrict__ lbl_g)
{
  __shared__ float redS[2][128];

  int tid = threadIdx.x;
  int wid = tid >> 6, lane = tid & 63;
  int quad = lane >> 4, c16 = lane & 15;
  int wm = wid & 1, wn = wid >> 1;
  int bid = blockIdx.x;
  int bm = ((bid >> 6) << 3) + (bid & 7);
  int bn = (bid >> 3) & 7;                       // 128-col strip
  int bu = bm >> 1, thalf = bm & 1;
  int b = bu / cU1, u = bu - b * cU1;
  int tg = (u < cU) ? targets[b * cU + u] : -1;
  int lin0 = bu * cT + thalf * 128;              // (b,u,t)-linear base

  f32x4 acc[4][4];
#pragma unroll
  for (int i = 0; i < 4; i++)
#pragma unroll
    for (int j = 0; j < 4; j++)
      acc[i][j] = (f32x4){0.f, 0.f, 0.f, 0.f};

  const uchar_t* aP = Hbf8 + (size_t)bm * 65536 + (wm * 4) * 1024 + lane * 16;
  const uchar_t* bP = WTf8 + (size_t)(bn >> 1) * 131072 + ((bn & 1) * 8 + wn * 4) * 1024 + lane * 16;

  v2i64 afX[4], bfX[4], afY[4], bfY[4];
#pragma unroll
  for (int mt = 0; mt < 4; mt++) afX[mt] = *(const v2i64*)(aP + mt * 1024);
#pragma unroll
  for (int nt = 0; nt < 4; nt++) bfX[nt] = *(const v2i64*)(bP + nt * 1024);

#pragma unroll
  for (int k2 = 0; k2 < 4; k2++){
    // ---- issue loads for ksp = 2*k2+1 (Y) a full MFMA stage early ----
    {
      size_t kY = (size_t)(2 * k2 + 1);
#pragma unroll
      for (int mt = 0; mt < 4; mt++) afY[mt] = *(const v2i64*)(aP + kY * 8192 + mt * 1024);
#pragma unroll
      for (int nt = 0; nt < 4; nt++) bfY[nt] = *(const v2i64*)(bP + kY * 16384 + nt * 1024);
    }
    // ---- MFMA on X (covers Y's load latency) ----
#pragma unroll
    for (int h = 0; h < 2; h++)
#pragma unroll
      for (int mt = 0; mt < 4; mt++)
#pragma unroll
        for (int nt = 0; nt < 4; nt++)
          acc[mt][nt] = __builtin_amdgcn_mfma_f32_16x16x32_fp8_fp8(afX[mt][h], bfX[nt][h], acc[mt][nt], 0, 0, 0);
    // ---- issue loads for ksp = 2*k2+2 (X), statically guarded ----
    if (k2 < 3){
      size_t kX = (size_t)(2 * k2 + 2);
#pragma unroll
      for (int mt = 0; mt < 4; mt++) afX[mt] = *(const v2i64*)(aP + kX * 8192 + mt * 1024);
#pragma unroll
      for (int nt = 0; nt < 4; nt++) bfX[nt] = *(const v2i64*)(bP + kX * 16384 + nt * 1024);
    }
    // ---- MFMA on Y (covers X's load latency) ----
#pragma unroll
    for (int h = 0; h < 2; h++)
#pragma unroll
      for (int mt = 0; mt < 4; mt++)
#pragma unroll
        for (int nt = 0; nt < 4; nt++)
          acc[mt][nt] = __builtin_amdgcn_mfma_f32_16x16x32_fp8_fp8(afY[mt][h], bfY[nt][h], acc[mt][nt], 0, 0, 0);
  }

  float bv[4];
#pragma unroll
  for (int nt = 0; nt < 4; nt++) bv[nt] = b_out[bn * 128 + (wn * 4 + nt) * 16 + c16] * LOG2E;

  bool ownL = (tg >= 0) && ((tg >> 7) == bn) && (((tg >> 6) & 1) == wn);
  int ntO = (tg >> 4) & 3;
  int tgc = tg & 15;
  const float descale2 = LOG2E / 32.f;  // undo *32 on W_out fp8 AND go log2-domain

#pragma unroll
  for (int mt = 0; mt < 4; mt++){
#pragma unroll
    for (int r = 0; r < 4; r++){
      int rl = wm * 64 + mt * 16 + quad * 4 + r;  // C/D: col=lane&15, row=quad*4+reg (m89)
      float l[4];
#pragma unroll
      for (int nt = 0; nt < 4; nt++) l[nt] = fmaf(acc[mt][nt][r], descale2, bv[nt]);
      if (bn == 0 && wn == 0 && c16 == 0) blank_g[lin0 + rl] = l[0];
      if (ownL && c16 == tgc){
        float v = l[0];
#pragma unroll
        for (int k = 1; k < 4; k++) v = (ntO == k) ? l[k] : v;
        lbl_g[lin0 + rl] = v;
      }
      float s = __builtin_amdgcn_exp2f(l[0]) + __builtin_amdgcn_exp2f(l[1])
              + __builtin_amdgcn_exp2f(l[2]) + __builtin_amdgcn_exp2f(l[3]);
      s += __shfl_xor(s, 1, 64);
      s += __shfl_xor(s, 2, 64);
      s += __shfl_xor(s, 4, 64);
      s += __shfl_xor(s, 8, 64);
      if (c16 == 0) redS[wn][rl] = s;
    }
  }
  __syncthreads();
  if (tid < 128)
    atomicAdd(&S[lin0 + tid], redS[0][tid] + redS[1][tid]);
}

// ------------- RNN-T alpha DP: SKIP-2 diagonals, log2 domain, fused-LSE staging -------------
// blank_g/lbl_g arrive ALREADY in log2 domain (k_joint epilogue) -> staging is
// just x - log2(S). Everything else as the verified r1 version.
__global__ __launch_bounds__(256) void k_dp(
    const float* __restrict__ S, const float* __restrict__ blank_g,
    const float* __restrict__ lbl_g,
    const int* __restrict__ in_len, const int* __restrict__ tgt_len,
    float* __restrict__ out)
{
  __shared__ float sbb[cTU];   // 65 KB, (u,t): index u*256+t  (log2 domain)
  __shared__ float slb[cTU];   // 65 KB
  __shared__ float sS[256];    // alpha[t][63] history (lane 63)
  int b = blockIdx.x;
  int tl  = tgt_len[b];                // 32..64
  size_t base = (size_t)b * cTU;
  for (int i = threadIdx.x; i < cTU / 4; i += 256){
    int row = i >> 6;                  // float4 never crosses a 256-elem row
    if (row > tl) continue;            // rows > tl unread by any live lane
    float4 sv = ((const float4*)(S + base))[i];
    float4 bvv = ((const float4*)(blank_g + base))[i];
    float4 ls;
    ls.x = __builtin_amdgcn_logf(sv.x); ls.y = __builtin_amdgcn_logf(sv.y);
    ls.z = __builtin_amdgcn_logf(sv.z); ls.w = __builtin_amdgcn_logf(sv.w);
    float4 bo;
    bo.x = bvv.x - ls.x; bo.y = bvv.y - ls.y;
    bo.z = bvv.z - ls.z; bo.w = bvv.w - ls.w;
    ((float4*)sbb)[i] = bo;
    float4 lo;
    if (row < tl){
      float4 lv = ((const float4*)(lbl_g + base))[i];
      lo.x = lv.x - ls.x; lo.y = lv.y - ls.y;
      lo.z = lv.z - ls.z; lo.w = lv.w - ls.w;
    } else {
      lo.x = NEGF; lo.y = NEGF; lo.z = NEGF; lo.w = NEGF;
    }
    ((float4*)slb)[i] = lo;
  }
  __syncthreads();
  if (threadIdx.x >= 64) return;

  int u = threadIdx.x;                 // 0..63
  int til = in_len[b] - 1;
  bool cap64 = (tl == 64);
  bool isTL = (u == tl);
  const float* pbu  = sbb + (u << 8);
  const float* pbu1 = sbb + (((u >= 1) ? u - 1 : 0) << 8);
  const float* plu1 = slb + (((u >= 1) ? u - 1 : 0) << 8);
  const float* plu2 = slb + (((u >= 2) ? u - 2 : 0) << 8);
  bool u1 = (u >= 1), u2 = (u >= 2);
  float fb = pbu[til];                 // blank at (u, til); used by lane tl only
  int shA1 = (u - 1) << 2;             // bpermute byte addrs; underflow wraps to
  int shA2 = (u - 2) << 2;             // lane 63 -> value killed by NEG masking

  float A = (u == 0) ? 0.f : NEGF;     // alpha on even diagonal d = 2g (log2)
  float res = 0.f;

  auto ld = [&](const float* p, int i, bool ok) -> float {
    float x = p[i & 255];              // wrap stays inside sbb/slb
    return (ok & ((unsigned)i < 256u)) ? x : NEGF;
  };

  int i0 = -u;
  float o0 = ld(pbu,  i0,     true);   // bb[t-2][u]
  float o1 = ld(pbu,  i0 + 1, true);   // bb[t-1][u]
  float o2 = ld(plu1, i0 + 1, u1);     // lb[t-1][u-1]
  float o3 = ld(pbu1, i0 + 1, u1);     // bb[t-1][u-1]
  float o4 = ld(plu1, i0 + 2, u1);     // lb[t][u-1]
  float o5 = ld(plu2, i0 + 2, u2);     // lb[t][u-2]

#pragma unroll 3
  for (int g = 0; g < 159; g++){
    // shuffles FIRST (depend on prev A) so the prefetch reads below stay behind
    // them in lgkm order -> waiting for up1/up2 is lgkmcnt(6), not a full drain
    float up1 = __int_as_float(__builtin_amdgcn_ds_bpermute(shA1, __float_as_int(A)));
    float up2 = __int_as_float(__builtin_amdgcn_ds_bpermute(shA2, __float_as_int(A)));

    int i0n = i0 + 2;
    float n0 = ld(pbu,  i0n,     true);
    float n1 = ld(pbu,  i0n + 1, true);
    float n2 = ld(plu1, i0n + 1, u1);
    float n3 = ld(pbu1, i0n + 1, u1);
    float n4 = ld(plu1, i0n + 2, u1);
    float n5 = ld(plu2, i0n + 2, u2);

    float C0 = o0 + o1;
    float C1 = logadd2(o2 + o1, o3 + o4);
    float C2 = o5 + o4;

    float am0 = A + o0, am1 = up1 + o2;
    float Amid = logadd2(am0, am1);
    bool tv1 = ((unsigned)(i0 + 1) < 256u);
    Amid = tv1 ? Amid : NEGF;

    float a0 = A + C0, a1 = up1 + C1, a2 = up2 + C2;
    float m3 = fmaxf(fmaxf(a0, a1), a2);          // v_max3
    float s3 = __builtin_amdgcn_exp2f(a0 - m3) + __builtin_amdgcn_exp2f(a1 - m3)
             + __builtin_amdgcn_exp2f(a2 - m3);
    float Anew = m3 + __builtin_amdgcn_logf(s3);
    bool tv2 = ((unsigned)(i0 + 2) < 256u);
    Anew = tv2 ? Anew : NEGF;

    if (isTL && (i0 + 1) == til) res = Amid + fb;
    if (isTL && (i0 + 2) == til) res = Anew + fb;
    if (u == 63){
      if (tv1) sS[i0 + 1] = Amid;
      if (tv2) sS[i0 + 2] = Anew;
    }
    A = Anew;
    i0 = i0n;
    o0 = n0; o1 = n1; o2 = n2; o3 = n3; o4 = n4; o5 = n5;
  }

  if (cap64){
    const float* pb64 = sbb + (64 << 8);
    const float* pl63 = slb + (63 << 8);
    float A64 = sS[0] + pl63[0];       // alpha[0][64]
    for (int t = 1; t <= til; t++)
      A64 = logadd2(A64 + pb64[t - 1], sS[t] + pl63[t]);
    if (u == 0) res = A64 + pb64[til];
  }

  // butterfly-sum broadcasts the single captured value (others hold 0)
  res += __shfl_xor(res, 1, 64);
  res += __shfl_xor(res, 2, 64);
  res += __shfl_xor(res, 4, 64);
  res += __shfl_xor(res, 8, 64);
  res += __shfl_xor(res, 16, 64);
  res += __shfl_xor(res, 32, 64);
  if (u == 0) atomicAdd(out, -0.17328679513998632f * res);  // -0.25 * ln2 (log2->ln)
}

extern "C" void kernel_launch(void* const* d_in, const int* in_sizes, int n_in,
                              void* d_out, int out_size, void* d_ws, size_t ws_size,
                              hipStream_t stream)
{
  (void)in_sizes; (void)n_in; (void)out_size; (void)ws_size;
  const float* inputs = (const float*)d_in[0];   // (4,256,80)
  const float* W_enc  = (const float*)d_in[1];   // (80,512)
  const float* emb    = (const float*)d_in[2];   // (1024,512)
  const float* W_jenc = (const float*)d_in[3];   // (512,512)
  const float* W_jdec = (const float*)d_in[4];   // (512,512)
  const float* b_j    = (const float*)d_in[5];   // (512)
  const float* W_out  = (const float*)d_in[6];   // (512,1024)
  const float* b_out  = (const float*)d_in[7];   // (1024)
  const int* targets  = (const int*)d_in[8];     // (4,64)
  const int* in_len   = (const int*)d_in[9];     // (4)
  const int* tgt_len  = (const int*)d_in[10];    // (4)

  char* w = (char*)d_ws;
  auto alloc = [&](size_t bytes){ char* p = w; w += (bytes + 255) & ~(size_t)255; return p; };
  float* e       = (float*)alloc((size_t)1024 * 512 * 4);
  float* dmatb   = (float*)alloc((size_t)260 * 512 * 4);
  float* blank_g = (float*)alloc((size_t)cM * 4);
  float* lbl_g   = (float*)alloc((size_t)cM * 4);
  float* S       = (float*)alloc((size_t)cM * 4);
  uchar_t* Hbf8  = (uchar_t*)alloc((size_t)520 * 65536);
  uchar_t* WTf8  = (uchar_t*)alloc((size_t)4 * 131072);

  k_pre<<<483, 256, 0, stream>>>(inputs, W_enc, W_jenc, emb, targets, W_jdec, b_j,
                                 dmatb, e, W_out, WTf8, S, (float*)d_out);
  k_hf<<<520, 256, 0, stream>>>(e, dmatb, Hbf8);
  k_joint<<<4160, 256, 0, stream>>>(Hbf8, WTf8, b_out, targets, S, blank_g, lbl_g);
  k_dp<<<4, 256, 0, stream>>>(S, blank_g, lbl_g, in_len, tgt_len, (float*)d_out);
}

// Round 7
// 223.192 us; speedup vs baseline: 1.2020x; 1.0011x over previous
//
#include <hip/hip_runtime.h>
#include <stdint.h>

#define NEGF (-1e30f)

typedef unsigned short ushort_t;
typedef unsigned char uchar_t;
typedef __attribute__((ext_vector_type(2))) long v2i64;
typedef __attribute__((ext_vector_type(4))) float f32x4;

constexpr int cB = 4, cT = 256, cU = 64, cU1 = 65, cV = 1024, cF = 80, cH = 512, cJ = 512;
constexpr int cM = cB * cT * cU1; // 66560
constexpr int cTU = cT * cU1;     // 16640 (per-batch (u,t) plane: u*256+t)
constexpr float LOG2E = 1.4426950408889634f;

// Padé(2,2) tanh + clamp: max err ~0.016, far below fp8-e4m3 half-step; no v_exp.
__device__ __forceinline__ float tanh_fast(float x){
  float t = x * x;
  float num = x * (27.f + t);
  float den = fmaf(9.f, t, 27.f);
  float r = num * __builtin_amdgcn_rcpf(den);
  return fminf(1.f, fmaxf(-1.f, r));
}

// log2-domain logadd: v_exp_f32/v_log_f32 ARE base-2 -> no ln2 scaling muls.
__device__ __forceinline__ float logadd2(float x, float y){
  float m = fmaxf(x, y);
  return m + __builtin_amdgcn_logf(1.f + __builtin_amdgcn_exp2f(-fabsf(x - y)));
}

// wave shift-right-by-1 via DPP (lane i <- lane i-1); invalid lane 0 reads 0.0f
// (bound_ctrl:0). 2-cycle VALU op -- replaces ds_bpermute (~100cy LDS latency)
// on k_dp's serial A->A critical path. Garbage-at-boundary is killed by the
// NEGF operand masking (o2/o3 at u<1, o5 at u<2), same as the old wrap path.
__device__ __forceinline__ float wshr1(float x){
  return __int_as_float(__builtin_amdgcn_mov_dpp(__float_as_int(x),
                                                 0x138, 0xF, 0xF, true));
}

__device__ __forceinline__ int pk8(float a, float b, float c, float d){
  int v = __builtin_amdgcn_cvt_pk_fp8_f32(a, b, 0, false);
  v = __builtin_amdgcn_cvt_pk_fp8_f32(c, d, v, true);
  return v;
}

// ------------- fused prologue: 4 independent jobs in one dispatch -------------
// bid 0..255  : e[4 rows] = (inputs @ W_enc) @ W_jenc, block-local two-stage
// bid 256..385: dmatb(260,512) = emb[padded] @ W_jdec + b_j
// bid 386..417: WTf8 fp8 fragment-order transpose of 32*W_out (2-ks-packed, K=32)
// bid 418..482: zero S[cM]; bid 418 also zeroes out[0] (k_dp atomic target)
__global__ __launch_bounds__(256) void k_pre(
    const float* __restrict__ inputs,
    const float* __restrict__ W_enc, const float* __restrict__ W_jenc,
    const float* __restrict__ emb, const int* __restrict__ targets,
    const float* __restrict__ W_jdec, const float* __restrict__ b_j,
    float* __restrict__ dmatb, float* __restrict__ e,
    const float* __restrict__ W_out, uchar_t* __restrict__ WTf8,
    float* __restrict__ S, float* __restrict__ out_loss)
{
  __shared__ float sA[4][512];
  __shared__ float sIn[4][80];
  int bid = blockIdx.x;
  int tid = threadIdx.x;

  if (bid < 256){
    // ---- e rows m0..m0+3 ----
    int m0 = bid * 4;
    // r20 BUG FIX: 320 elements with 256 threads needs a strided loop (the
    // single `if (tid < 320)` left sIn[3][16..79] uninitialized -> absmax 16).
    for (int i = tid; i < 320; i += 256)
      sIn[i / 80][i % 80] = inputs[m0 * 80 + i];
    __syncthreads();
    int c0 = tid, c1 = tid + 256;
    float a00 = 0.f, a01 = 0.f, a10 = 0.f, a11 = 0.f;
    float a20 = 0.f, a21 = 0.f, a30 = 0.f, a31 = 0.f;
#pragma unroll 8
    for (int k = 0; k < 80; k++){
      float w0 = W_enc[(size_t)k * 512 + c0];
      float w1 = W_enc[(size_t)k * 512 + c1];
      a00 = fmaf(sIn[0][k], w0, a00); a01 = fmaf(sIn[0][k], w1, a01);
      a10 = fmaf(sIn[1][k], w0, a10); a11 = fmaf(sIn[1][k], w1, a11);
      a20 = fmaf(sIn[2][k], w0, a20); a21 = fmaf(sIn[2][k], w1, a21);
      a30 = fmaf(sIn[3][k], w0, a30); a31 = fmaf(sIn[3][k], w1, a31);
    }
    sA[0][c0] = a00; sA[0][c1] = a01;
    sA[1][c0] = a10; sA[1][c1] = a11;
    sA[2][c0] = a20; sA[2][c1] = a21;
    sA[3][c0] = a30; sA[3][c1] = a31;
    __syncthreads();
    float b00 = 0.f, b01 = 0.f, b10 = 0.f, b11 = 0.f;
    float b20 = 0.f, b21 = 0.f, b30 = 0.f, b31 = 0.f;
#pragma unroll 8
    for (int k = 0; k < 512; k++){
      float w0 = W_jenc[(size_t)k * 512 + c0];
      float w1 = W_jenc[(size_t)k * 512 + c1];
      b00 = fmaf(sA[0][k], w0, b00); b01 = fmaf(sA[0][k], w1, b01);
      b10 = fmaf(sA[1][k], w0, b10); b11 = fmaf(sA[1][k], w1, b11);
      b20 = fmaf(sA[2][k], w0, b20); b21 = fmaf(sA[2][k], w1, b21);
      b30 = fmaf(sA[3][k], w0, b30); b31 = fmaf(sA[3][k], w1, b31);
    }
    e[(size_t)(m0 + 0) * 512 + c0] = b00; e[(size_t)(m0 + 0) * 512 + c1] = b01;
    e[(size_t)(m0 + 1) * 512 + c0] = b10; e[(size_t)(m0 + 1) * 512 + c1] = b11;
    e[(size_t)(m0 + 2) * 512 + c0] = b20; e[(size_t)(m0 + 2) * 512 + c1] = b21;
    e[(size_t)(m0 + 3) * 512 + c0] = b30; e[(size_t)(m0 + 3) * 512 + c1] = b31;
  } else if (bid < 386){
    // ---- dmatb = emb[padded] @ W_jdec + b_j ----
    int id = bid - 256;                  // 0..129
    int bx = id & 1, by = id >> 1;
    int m0 = by * 4;
    int col = bx * 256 + tid;
    for (int i = tid; i < 4 * 512; i += 256){
      int r = i >> 9, c = i & 511;
      int row = m0 + r;
      int b = row / cU1, u = row % cU1;
      int src = (u == 0) ? 0 : targets[b * cU + (u - 1)];
      sA[r][c] = emb[(size_t)src * cH + c];
    }
    __syncthreads();
    float a0 = 0.f, a1 = 0.f, a2 = 0.f, a3 = 0.f;
#pragma unroll 8
    for (int k = 0; k < 512; k++){
      float bv = W_jdec[(size_t)k * cJ + col];
      a0 = fmaf(sA[0][k], bv, a0);
      a1 = fmaf(sA[1][k], bv, a1);
      a2 = fmaf(sA[2][k], bv, a2);
      a3 = fmaf(sA[3][k], bv, a3);
    }
    float bb = b_j[col];
    dmatb[(size_t)(m0 + 0) * cJ + col] = a0 + bb;
    dmatb[(size_t)(m0 + 1) * cJ + col] = a1 + bb;
    dmatb[(size_t)(m0 + 2) * cJ + col] = a2 + bb;
    dmatb[(size_t)(m0 + 3) * cJ + col] = a3 + bb;
  } else if (bid < 418){
    // ---- WTf8[((bn4*8+ksp)*16 + nt16)*1024 + lane*16]  (K=32, 2-ks-packed) ----
    int id = bid - 386;                  // 0..31
    int bn = id & 3, ksp = id >> 2;      // ksp 0..7
    int lane = tid & 63, nth = tid >> 6;
    int c16 = lane & 15, quad = lane >> 4;
    int jA = ksp * 64 + quad * 8;
#pragma unroll
    for (int i = 0; i < 4; i++){
      int nt16 = nth * 4 + i;
      int n = bn * 256 + nt16 * 16 + c16;
      unsigned int p[4];
#pragma unroll
      for (int h = 0; h < 4; h++){
        int j0 = jA + (h >> 1) * 32 + (h & 1) * 4;
        float w0 = W_out[(size_t)(j0 + 0) * cV + n] * 32.f;
        float w1 = W_out[(size_t)(j0 + 1) * cV + n] * 32.f;
        float w2 = W_out[(size_t)(j0 + 2) * cV + n] * 32.f;
        float w3 = W_out[(size_t)(j0 + 3) * cV + n] * 32.f;
        p[h] = (unsigned)pk8(w0, w1, w2, w3);
      }
      uint4 pack; pack.x = p[0]; pack.y = p[1]; pack.z = p[2]; pack.w = p[3];
      *(uint4*)(WTf8 + (((size_t)(bn * 8 + ksp) * 16 + nt16) * 64 + lane) * 16) = pack;
    }
  } else {
    // ---- zero S: 65 blocks x 256 thr x 4 floats = 66560 ----
    int i = (bid - 418) * 1024 + tid * 4;
    float4 z; z.x = 0.f; z.y = 0.f; z.z = 0.f; z.w = 0.f;
    *(float4*)(S + i) = z;
    if (bid == 418 && tid == 0) out_loss[0] = 0.f;
  }
}

// ------------- H fp8 fragment-order (K=32), t-minor, coalesced via LDS bounce -------------
__global__ __launch_bounds__(256) void k_hf(const float* __restrict__ e,
                                            const float* __restrict__ dmatb,
                                            uchar_t* __restrict__ Hbf8){
  __shared__ uchar_t sH[16 * 520];    // 16 rows x 512 B, pad 8 B
  int tid = threadIdx.x;
  int wid = tid >> 6, lane = tid & 63;
  int c16 = lane & 15, quad = lane >> 4;
  int bm = blockIdx.x;
  int bu = bm >> 1, thalf = bm & 1;
  int b = bu / cU1;
  int t0 = thalf * 128;

  float dj[8];
  const float4* dp = (const float4*)(dmatb + (size_t)bu * cJ + lane * 8);
  float4 dA = dp[0], dB = dp[1];
  dj[0] = dA.x; dj[1] = dA.y; dj[2] = dA.z; dj[3] = dA.w;
  dj[4] = dB.x; dj[5] = dB.y; dj[6] = dB.z; dj[7] = dB.w;

  const float* erow0 = e + ((size_t)(b * cT + t0)) * cJ + lane * 8;
  uchar_t* outb = Hbf8 + (size_t)bm * 65536 + lane * 16;

  for (int mg = 0; mg < 8; mg++){
#pragma unroll
    for (int rr = 0; rr < 4; rr++){
      int rloc = wid * 4 + rr;
      const float* ep = erow0 + ((size_t)(mg * 16 + rloc)) * cJ;
      float4 e0 = *(const float4*)ep;
      float4 e1 = *(const float4*)(ep + 4);
      int v0 = pk8(tanh_fast(e0.x + dj[0]), tanh_fast(e0.y + dj[1]),
                   tanh_fast(e0.z + dj[2]), tanh_fast(e0.w + dj[3]));
      int v1 = pk8(tanh_fast(e1.x + dj[4]), tanh_fast(e1.y + dj[5]),
                   tanh_fast(e1.z + dj[6]), tanh_fast(e1.w + dj[7]));
      uint2 pk; pk.x = (unsigned)v0; pk.y = (unsigned)v1;
      *(uint2*)(sH + rloc * 520 + lane * 8) = pk;
    }
    __syncthreads();
#pragma unroll
    for (int q = 0; q < 2; q++){
      int ksp = wid * 2 + q;
      uint2 lo = *(const uint2*)(sH + c16 * 520 + ksp * 64 + quad * 8);
      uint2 hi = *(const uint2*)(sH + c16 * 520 + ksp * 64 + 32 + quad * 8);
      uint4 pack; pack.x = lo.x; pack.y = lo.y; pack.z = hi.x; pack.w = hi.y;
      *(uint4*)(outb + ((size_t)ksp * 8 + mg) * 1024) = pack;
    }
    __syncthreads();
  }
}

// ------------- joint GEMM fp8 K=32: 64x64 wave tile (r6 body, measured 60us) -------------
// r6 POST-MORTEM: X/Y pipeline was re-serialized by the compiler (VGPR still
// 60, dur unchanged) -- source-level SW pipelining is defeated (guide CM#5).
// Left byte-identical this round; next lever here is LDS-staged B + phase
// structure if k_joint re-emerges as the top cost after k_dp lands.
__global__ __launch_bounds__(256, 3) void k_joint(
    const uchar_t* __restrict__ Hbf8, const uchar_t* __restrict__ WTf8,
    const float* __restrict__ b_out, const int* __restrict__ targets,
    float* __restrict__ S,
    float* __restrict__ blank_g, float* __restrict__ lbl_g)
{
  __shared__ float redS[2][128];

  int tid = threadIdx.x;
  int wid = tid >> 6, lane = tid & 63;
  int quad = lane >> 4, c16 = lane & 15;
  int wm = wid & 1, wn = wid >> 1;
  int bid = blockIdx.x;
  int bm = ((bid >> 6) << 3) + (bid & 7);
  int bn = (bid >> 3) & 7;                       // 128-col strip
  int bu = bm >> 1, thalf = bm & 1;
  int b = bu / cU1, u = bu - b * cU1;
  int tg = (u < cU) ? targets[b * cU + u] : -1;
  int lin0 = bu * cT + thalf * 128;              // (b,u,t)-linear base

  f32x4 acc[4][4];
#pragma unroll
  for (int i = 0; i < 4; i++)
#pragma unroll
    for (int j = 0; j < 4; j++)
      acc[i][j] = (f32x4){0.f, 0.f, 0.f, 0.f};

  const uchar_t* aP = Hbf8 + (size_t)bm * 65536 + (wm * 4) * 1024 + lane * 16;
  const uchar_t* bP = WTf8 + (size_t)(bn >> 1) * 131072 + ((bn & 1) * 8 + wn * 4) * 1024 + lane * 16;

  v2i64 afX[4], bfX[4], afY[4], bfY[4];
#pragma unroll
  for (int mt = 0; mt < 4; mt++) afX[mt] = *(const v2i64*)(aP + mt * 1024);
#pragma unroll
  for (int nt = 0; nt < 4; nt++) bfX[nt] = *(const v2i64*)(bP + nt * 1024);

#pragma unroll
  for (int k2 = 0; k2 < 4; k2++){
    // ---- issue loads for ksp = 2*k2+1 (Y) a full MFMA stage early ----
    {
      size_t kY = (size_t)(2 * k2 + 1);
#pragma unroll
      for (int mt = 0; mt < 4; mt++) afY[mt] = *(const v2i64*)(aP + kY * 8192 + mt * 1024);
#pragma unroll
      for (int nt = 0; nt < 4; nt++) bfY[nt] = *(const v2i64*)(bP + kY * 16384 + nt * 1024);
    }
    // ---- MFMA on X (covers Y's load latency) ----
#pragma unroll
    for (int h = 0; h < 2; h++)
#pragma unroll
      for (int mt = 0; mt < 4; mt++)
#pragma unroll
        for (int nt = 0; nt < 4; nt++)
          acc[mt][nt] = __builtin_amdgcn_mfma_f32_16x16x32_fp8_fp8(afX[mt][h], bfX[nt][h], acc[mt][nt], 0, 0, 0);
    // ---- issue loads for ksp = 2*k2+2 (X), statically guarded ----
    if (k2 < 3){
      size_t kX = (size_t)(2 * k2 + 2);
#pragma unroll
      for (int mt = 0; mt < 4; mt++) afX[mt] = *(const v2i64*)(aP + kX * 8192 + mt * 1024);
#pragma unroll
      for (int nt = 0; nt < 4; nt++) bfX[nt] = *(const v2i64*)(bP + kX * 16384 + nt * 1024);
    }
    // ---- MFMA on Y (covers X's load latency) ----
#pragma unroll
    for (int h = 0; h < 2; h++)
#pragma unroll
      for (int mt = 0; mt < 4; mt++)
#pragma unroll
        for (int nt = 0; nt < 4; nt++)
          acc[mt][nt] = __builtin_amdgcn_mfma_f32_16x16x32_fp8_fp8(afY[mt][h], bfY[nt][h], acc[mt][nt], 0, 0, 0);
  }

  float bv[4];
#pragma unroll
  for (int nt = 0; nt < 4; nt++) bv[nt] = b_out[bn * 128 + (wn * 4 + nt) * 16 + c16] * LOG2E;

  bool ownL = (tg >= 0) && ((tg >> 7) == bn) && (((tg >> 6) & 1) == wn);
  int ntO = (tg >> 4) & 3;
  int tgc = tg & 15;
  const float descale2 = LOG2E / 32.f;  // undo *32 on W_out fp8 AND go log2-domain

#pragma unroll
  for (int mt = 0; mt < 4; mt++){
#pragma unroll
    for (int r = 0; r < 4; r++){
      int rl = wm * 64 + mt * 16 + quad * 4 + r;  // C/D: col=lane&15, row=quad*4+reg (m89)
      float l[4];
#pragma unroll
      for (int nt = 0; nt < 4; nt++) l[nt] = fmaf(acc[mt][nt][r], descale2, bv[nt]);
      if (bn == 0 && wn == 0 && c16 == 0) blank_g[lin0 + rl] = l[0];
      if (ownL && c16 == tgc){
        float v = l[0];
#pragma unroll
        for (int k = 1; k < 4; k++) v = (ntO == k) ? l[k] : v;
        lbl_g[lin0 + rl] = v;
      }
      float s = __builtin_amdgcn_exp2f(l[0]) + __builtin_amdgcn_exp2f(l[1])
              + __builtin_amdgcn_exp2f(l[2]) + __builtin_amdgcn_exp2f(l[3]);
      s += __shfl_xor(s, 1, 64);
      s += __shfl_xor(s, 2, 64);
      s += __shfl_xor(s, 4, 64);
      s += __shfl_xor(s, 8, 64);
      if (c16 == 0) redS[wn][rl] = s;
    }
  }
  __syncthreads();
  if (tid < 128)
    atomicAdd(&S[lin0 + tid], redS[0][tid] + redS[1][tid]);
}

// ------------- RNN-T alpha DP: SKIP-2 diagonals, log2 domain, DPP shuffles -------------
// r7: the serial A->A chain no longer touches LDS. up1/up2 via v_mov_b32_dpp
// wave_shr:1 (2cy VALU) instead of ds_bpermute (~100cy). The 6 ds_read
// prefetches are the only LDS ops left and are issued one iteration early,
// fully off the critical path.
__global__ __launch_bounds__(256) void k_dp(
    const float* __restrict__ S, const float* __restrict__ blank_g,
    const float* __restrict__ lbl_g,
    const int* __restrict__ in_len, const int* __restrict__ tgt_len,
    float* __restrict__ out)
{
  __shared__ float sbb[cTU];   // 65 KB, (u,t): index u*256+t  (log2 domain)
  __shared__ float slb[cTU];   // 65 KB
  __shared__ float sS[256];    // alpha[t][63] history (lane 63)
  int b = blockIdx.x;
  int tl  = tgt_len[b];                // 32..64
  size_t base = (size_t)b * cTU;
  for (int i = threadIdx.x; i < cTU / 4; i += 256){
    int row = i >> 6;                  // float4 never crosses a 256-elem row
    if (row > tl) continue;            // rows > tl unread by any live lane
    float4 sv = ((const float4*)(S + base))[i];
    float4 bvv = ((const float4*)(blank_g + base))[i];
    float4 ls;
    ls.x = __builtin_amdgcn_logf(sv.x); ls.y = __builtin_amdgcn_logf(sv.y);
    ls.z = __builtin_amdgcn_logf(sv.z); ls.w = __builtin_amdgcn_logf(sv.w);
    float4 bo;
    bo.x = bvv.x - ls.x; bo.y = bvv.y - ls.y;
    bo.z = bvv.z - ls.z; bo.w = bvv.w - ls.w;
    ((float4*)sbb)[i] = bo;
    float4 lo;
    if (row < tl){
      float4 lv = ((const float4*)(lbl_g + base))[i];
      lo.x = lv.x - ls.x; lo.y = lv.y - ls.y;
      lo.z = lv.z - ls.z; lo.w = lv.w - ls.w;
    } else {
      lo.x = NEGF; lo.y = NEGF; lo.z = NEGF; lo.w = NEGF;
    }
    ((float4*)slb)[i] = lo;
  }
  __syncthreads();
  if (threadIdx.x >= 64) return;

  int u = threadIdx.x;                 // 0..63
  int til = in_len[b] - 1;
  bool cap64 = (tl == 64);
  bool isTL = (u == tl);
  const float* pbu  = sbb + (u << 8);
  const float* pbu1 = sbb + (((u >= 1) ? u - 1 : 0) << 8);
  const float* plu1 = slb + (((u >= 1) ? u - 1 : 0) << 8);
  const float* plu2 = slb + (((u >= 2) ? u - 2 : 0) << 8);
  bool u1 = (u >= 1), u2 = (u >= 2);
  float fb = pbu[til];                 // blank at (u, til); used by lane tl only

  float A = (u == 0) ? 0.f : NEGF;     // alpha on even diagonal d = 2g (log2)
  float res = 0.f;

  auto ld = [&](const float* p, int i, bool ok) -> float {
    float x = p[i & 255];              // wrap stays inside sbb/slb
    return (ok & ((unsigned)i < 256u)) ? x : NEGF;
  };

  int i0 = -u;
  float o0 = ld(pbu,  i0,     true);   // bb[t-2][u]
  float o1 = ld(pbu,  i0 + 1, true);   // bb[t-1][u]
  float o2 = ld(plu1, i0 + 1, u1);     // lb[t-1][u-1]
  float o3 = ld(pbu1, i0 + 1, u1);     // bb[t-1][u-1]
  float o4 = ld(plu1, i0 + 2, u1);     // lb[t][u-1]
  float o5 = ld(plu2, i0 + 2, u2);     // lb[t][u-2]

#pragma unroll 3
  for (int g = 0; g < 159; g++){
    // up1/up2 via DPP: pure VALU, ~4cy total, no lgkmcnt on the A->A path.
    // Lane 0 (and lane 1 for up2) read 0.0 -- killed by NEGF in o2/o3/C1,
    // o5/C2 exactly as the old bpermute-wrap garbage was.
    float up1 = wshr1(A);
    float up2 = wshr1(up1);

    int i0n = i0 + 2;
    float n0 = ld(pbu,  i0n,     true);
    float n1 = ld(pbu,  i0n + 1, true);
    float n2 = ld(plu1, i0n + 1, u1);
    float n3 = ld(pbu1, i0n + 1, u1);
    float n4 = ld(plu1, i0n + 2, u1);
    float n5 = ld(plu2, i0n + 2, u2);

    float C0 = o0 + o1;
    float C1 = logadd2(o2 + o1, o3 + o4);
    float C2 = o5 + o4;

    float am0 = A + o0, am1 = up1 + o2;
    float Amid = logadd2(am0, am1);
    bool tv1 = ((unsigned)(i0 + 1) < 256u);
    Amid = tv1 ? Amid : NEGF;

    float a0 = A + C0, a1 = up1 + C1, a2 = up2 + C2;
    float m3 = fmaxf(fmaxf(a0, a1), a2);          // v_max3
    float s3 = __builtin_amdgcn_exp2f(a0 - m3) + __builtin_amdgcn_exp2f(a1 - m3)
             + __builtin_amdgcn_exp2f(a2 - m3);
    float Anew = m3 + __builtin_amdgcn_logf(s3);
    bool tv2 = ((unsigned)(i0 + 2) < 256u);
    Anew = tv2 ? Anew : NEGF;

    if (isTL && (i0 + 1) == til) res = Amid + fb;
    if (isTL && (i0 + 2) == til) res = Anew + fb;
    if (u == 63){
      if (tv1) sS[i0 + 1] = Amid;
      if (tv2) sS[i0 + 2] = Anew;
    }
    A = Anew;
    i0 = i0n;
    o0 = n0; o1 = n1; o2 = n2; o3 = n3; o4 = n4; o5 = n5;
  }

  if (cap64){
    const float* pb64 = sbb + (64 << 8);
    const float* pl63 = slb + (63 << 8);
    float A64 = sS[0] + pl63[0];       // alpha[0][64]
    for (int t = 1; t <= til; t++)
      A64 = logadd2(A64 + pb64[t - 1], sS[t] + pl63[t]);
    if (u == 0) res = A64 + pb64[til];
  }

  // butterfly-sum broadcasts the single captured value (others hold 0)
  res += __shfl_xor(res, 1, 64);
  res += __shfl_xor(res, 2, 64);
  res += __shfl_xor(res, 4, 64);
  res += __shfl_xor(res, 8, 64);
  res += __shfl_xor(res, 16, 64);
  res += __shfl_xor(res, 32, 64);
  if (u == 0) atomicAdd(out, -0.17328679513998632f * res);  // -0.25 * ln2 (log2->ln)
}

extern "C" void kernel_launch(void* const* d_in, const int* in_sizes, int n_in,
                              void* d_out, int out_size, void* d_ws, size_t ws_size,
                              hipStream_t stream)
{
  (void)in_sizes; (void)n_in; (void)out_size; (void)ws_size;
  const float* inputs = (const float*)d_in[0];   // (4,256,80)
  const float* W_enc  = (const float*)d_in[1];   // (80,512)
  const float* emb    = (const float*)d_in[2];   // (1024,512)
  const float* W_jenc = (const float*)d_in[3];   // (512,512)
  const float* W_jdec = (const float*)d_in[4];   // (512,512)
  const float* b_j    = (const float*)d_in[5];   // (512)
  const float* W_out  = (const float*)d_in[6];   // (512,1024)
  const float* b_out  = (const float*)d_in[7];   // (1024)
  const int* targets  = (const int*)d_in[8];     // (4,64)
  const int* in_len   = (const int*)d_in[9];     // (4)
  const int* tgt_len  = (const int*)d_in[10];    // (4)

  char* w = (char*)d_ws;
  auto alloc = [&](size_t bytes){ char* p = w; w += (bytes + 255) & ~(size_t)255; return p; };
  float* e       = (float*)alloc((size_t)1024 * 512 * 4);
  float* dmatb   = (float*)alloc((size_t)260 * 512 * 4);
  float* blank_g = (float*)alloc((size_t)cM * 4);
  float* lbl_g   = (float*)alloc((size_t)cM * 4);
  float* S       = (float*)alloc((size_t)cM * 4);
  uchar_t* Hbf8  = (uchar_t*)alloc((size_t)520 * 65536);
  uchar_t* WTf8  = (uchar_t*)alloc((size_t)4 * 131072);

  k_pre<<<483, 256, 0, stream>>>(inputs, W_enc, W_jenc, emb, targets, W_jdec, b_j,
                                 dmatb, e, W_out, WTf8, S, (float*)d_out);
  k_hf<<<520, 256, 0, stream>>>(e, dmatb, Hbf8);
  k_joint<<<4160, 256, 0, stream>>>(Hbf8, WTf8, b_out, targets, S, blank_g, lbl_g);
  k_dp<<<4, 256, 0, stream>>>(S, blank_g, lbl_g, in_len, tgt_len, (float*)d_out);
}